// Round 10
// baseline (1252.846 us; speedup 1.0000x reference)
//
#include <hip/hip_runtime.h>

// ---------------- ws layout (float offsets) ----------------
#define O_WC     16
#define O_BC     (16 + 8192)
#define O_BIAS   (O_BC + 64)
#define O_BLEND1 16384
#define O_WB     3293184        // packed hi/lo weights (ushort region), 409600 floats
#define O_XW     4194304        // xw table [1024][50][1024] fp32 (use_xw only)
#define XW_FLOATS 52428800ULL
#define NEG_INF_V (-1.0e9f)

// packed weight region (ushort offsets). Gate tile nt (0..63) stride WB_TILE:
//   [0,4096) hhH kc*512+lane*8+e | [4096,8192) hhL
//   [8192,10240) ihH kc*512+lane*8+e | [10240,12288) ihL
// W2 tile ntw (0..3) at WB_W2 + ntw*8192: [0,4096) hi, [4096,8192) lo.
#define WB_TILE 12288
#define WB_W2   786432

using bf16x8 = __attribute__((ext_vector_type(8))) __bf16;
using f32x4  = __attribute__((ext_vector_type(4))) float;

__device__ __forceinline__ f32x4 mfma16(bf16x8 a, bf16x8 b, f32x4 c) {
  return __builtin_amdgcn_mfma_f32_16x16x32_bf16(a, b, c, 0, 0, 0);
}

__device__ __forceinline__ float b2f(unsigned int u) {
  union { unsigned int i; float f; } x; x.i = u << 16; return x.f;
}
__device__ __forceinline__ unsigned short f2b(float f) {
  union { float f; unsigned int i; } x; x.f = f;
  unsigned int r = x.i + 0x7fffu + ((x.i >> 16) & 1u);
  return (unsigned short)(r >> 16);
}
__device__ __forceinline__ float ldv(const void* p, int b16, long long i) {
  if (b16) return b2f(((const unsigned short*)p)[i]);
  return ((const float*)p)[i];
}
__device__ __forceinline__ float sigm(float x)  { return 1.0f / (1.0f + __expf(-x)); }
__device__ __forceinline__ float tanhx(float x) { return 1.0f - 2.0f / (1.0f + __expf(2.0f * x)); }

__device__ __forceinline__ float bfsel(const uint4& u, int e) {
  unsigned int w = (e < 2) ? u.x : (e < 4) ? u.y : (e < 6) ? u.z : u.w;
  union { unsigned int i; float f; } x;
  x.i = (e & 1) ? (w & 0xffff0000u) : (w << 16);
  return x.f;
}

// ---------------- prep0: dtype detect + bias + bc ----------------
__global__ void prep0(const void* b_enc, const void* b_ih, const void* b_hh,
                      const void* W1, float* ws) {
  __shared__ int anybig;
  int t = threadIdx.x;
  if (t == 0) anybig = 0;
  __syncthreads();
  {
    unsigned short u = ((const unsigned short*)b_enc)[t];
    float f = b2f((unsigned int)u);
    if (!(fabsf(f) <= 1.0f)) atomicOr(&anybig, 1);
  }
  __syncthreads();
  int b16 = anybig ? 0 : 1;
  if (t == 0) ((int*)ws)[0] = b16;
  for (int k = t; k < 1024; k += 256)
    ws[O_BIAS + k] = ldv(b_ih, b16, k) + ldv(b_hh, b16, k);
  if (t < 64) {
    float acc = 0.f;
    for (int h = 0; h < 256; ++h)
      acc += ldv(W1, b16, t * 256 + h) * ldv(b_enc, b16, h);
    ws[O_BC + t] = acc;
  }
}

// ---------------- prep1: Wc = W1 @ W_enc ----------------
__global__ void prep1(const void* W_enc, const void* W1, float* ws) {
  int b16 = ((const int*)ws)[0];
  int o = blockIdx.x * 256 + threadIdx.x;
  int w = o >> 7, i = o & 127;
  float acc = 0.f;
  for (int h = 0; h < 256; ++h)
    acc += ldv(W1, b16, w * 256 + h) * ldv(W_enc, b16, h * 128 + i);
  ws[O_WC + o] = acc;
}

// ---------------- wprep: hi/lo decomposition, packed coalesced layout ---------
__global__ __launch_bounds__(256) void wprep(const void* W_ih, const void* W_hh,
                                             const void* W2, float* ws) {
  const int b16 = ((const int*)ws)[0];
  unsigned short* wb = (unsigned short*)(ws + O_WB);
  int i = blockIdx.x * 256 + threadIdx.x;
  {  // W_hh [1024][256]
    int g = i >> 8, k = i & 255;
    int nt = g >> 4, r = g & 15;
    int kc = k >> 5, lane = ((k >> 3) & 3) * 16 + r, e = k & 7;
    float w = ldv(W_hh, b16, i);
    unsigned short hi = f2b(w);
    long long d = (long long)nt * WB_TILE + kc * 512 + lane * 8 + e;
    wb[d] = hi;
    wb[d + 4096] = f2b(w - b2f((unsigned int)hi));
  }
  if (i < 131072) {  // W_ih [1024][128]
    int g = i >> 7, k = i & 127;
    int nt = g >> 4, r = g & 15;
    int kc = k >> 5, lane = ((k >> 3) & 3) * 16 + r, e = k & 7;
    float w = ldv(W_ih, b16, i);
    unsigned short hi = f2b(w);
    long long d = (long long)nt * WB_TILE + 8192 + kc * 512 + lane * 8 + e;
    wb[d] = hi;
    wb[d + 2048] = f2b(w - b2f((unsigned int)hi));
  }
  if (i < 16384) {   // W2 [64][256]
    int g = i >> 8, k = i & 255;
    int ntw = g >> 4, r = g & 15;
    int kc = k >> 5, lane = ((k >> 3) & 3) * 16 + r, e = k & 7;
    float w = ldv(W2, b16, i);
    unsigned short hi = f2b(w);
    long long d = WB_W2 + ntw * 8192 + kc * 512 + lane * 8 + e;
    wb[d] = hi;
    wb[d + 4096] = f2b(w - b2f((unsigned int)hi));
  }
}

// ---------------- blendk: blend1 = targets @ Wc^T + bc ----------------
__global__ __launch_bounds__(256) void blendk(const void* targets, float* ws) {
  __shared__ float tg[6400];
  __shared__ float wc[8192];
  int b16 = ((const int*)ws)[0];
  int t = threadIdx.x, b = blockIdx.x;
  for (int k = t; k < 8192; k += 256) wc[k] = ws[O_WC + k];
  if (b16) {
    const unsigned short* tp = (const unsigned short*)targets + (long long)b * 6400;
    for (int k = t * 8; k < 6400; k += 2048) {
      uint4 u = *(const uint4*)(tp + k);
      #pragma unroll
      for (int e = 0; e < 8; ++e) tg[k + e] = bfsel(u, e);
    }
  } else {
    const float* tp = (const float*)targets + (long long)b * 6400;
    for (int k = t; k < 6400; k += 256) tg[k] = tp[k];
  }
  __syncthreads();
  int w = t & 63, j0 = t >> 6;
  float bcv = ws[O_BC + w];
  for (int j = j0; j < 50; j += 4) {
    float acc = 0.f;
    for (int i0 = 0; i0 < 128; i0 += 8) {
      const float4* q = (const float4*)(wc + w * 128 + i0);
      float4 a = q[0], bb = q[1];
      const float* x = &tg[j * 128 + i0];
      acc += a.x * x[0] + a.y * x[1] + a.z * x[2] + a.w * x[3]
           + bb.x * x[4] + bb.y * x[5] + bb.z * x[6] + bb.w * x[7];
    }
    ws[O_BLEND1 + (b * 50 + j) * 64 + w] = acc + bcv;
  }
}

// ---------------- xwK: xw[b][j][g] = targets[b,j,:].W_ih[g,:] (hi/lo MFMA) ----
__global__ __launch_bounds__(512)
__attribute__((amdgpu_waves_per_eu(2, 2)))
void xwK(const void* targets, float* ws) {
  __shared__ __align__(16) unsigned short tgS[4][32][264]; // hi 0-127, lo 128-255
  const int b16 = ((const int*)ws)[0];
  const int t = threadIdx.x;
  const int b0 = blockIdx.x * 4;
  const unsigned short* wb = (const unsigned short*)(ws + O_WB);
  float* xwp = ws + O_XW;
  const int l = t & 63, Wv = t >> 6, lr = l & 15, hc = l >> 4;

  #pragma unroll 1
  for (int half = 0; half < 2; ++half) {
    __syncthreads();
    for (int k = t; k < 4 * 32 * 128; k += 512) {
      int p = k >> 12, jr = (k >> 7) & 31, i = k & 127;
      int j = half * 32 + jr;
      float v = (j < 50) ? ldv(targets, b16, ((long long)(b0 + p) * 50 + j) * 128 + i)
                         : 0.f;
      unsigned short hi = f2b(v);
      tgS[p][jr][i]       = hi;
      tgS[p][jr][128 + i] = f2b(v - b2f((unsigned int)hi));
    }
    __syncthreads();
    const int njg = (half == 0) ? 4 : 3;
    #pragma unroll 1
    for (int ti = 0; ti < 8; ++ti) {
      const int nt = Wv * 8 + ti;
      const unsigned short* tb = wb + (long long)nt * WB_TILE + 8192 + l * 8;
      bf16x8 wih[8];
      #pragma unroll
      for (int kc = 0; kc < 4; ++kc) {
        wih[kc]     = *(const bf16x8*)(tb + kc * 512);
        wih[4 + kc] = *(const bf16x8*)(tb + 2048 + kc * 512);
      }
      #pragma unroll 1
      for (int p = 0; p < 4; ++p) {
        #pragma unroll 1
        for (int jh = 0; jh < njg; ++jh) {
          bf16x8 ax[4];
          const unsigned short* tp =
              &tgS[p][jh * 8 + (lr & 7)][((lr < 8) ? 0 : 128) + hc * 8];
          #pragma unroll
          for (int kc = 0; kc < 4; ++kc) ax[kc] = *(const bf16x8*)(tp + kc * 32);
          f32x4 cH = {0.f,0.f,0.f,0.f}, cL = {0.f,0.f,0.f,0.f};
          #pragma unroll
          for (int kc = 0; kc < 4; ++kc) {
            cH = mfma16(ax[kc], wih[kc], cH);
            cL = mfma16(ax[kc], wih[4 + kc], cL);
          }
          f32x4 acc = cH + cL;
          float s0 = acc[0] + __shfl_xor(acc[0], 32, 64);
          float s1 = acc[1] + __shfl_xor(acc[1], 32, 64);
          float s2 = acc[2] + __shfl_xor(acc[2], 32, 64);
          float s3 = acc[3] + __shfl_xor(acc[3], 32, 64);
          if (l < 32) {
            int jb = half * 32 + jh * 8 + hc * 4;
            long long ro = (long long)(b0 + p) * 50;
            if (jb + 0 < 50) xwp[(ro + jb + 0) * 1024 + nt * 16 + lr] = s0;
            if (jb + 1 < 50) xwp[(ro + jb + 1) * 1024 + nt * 16 + lr] = s1;
            if (jb + 2 < 50) xwp[(ro + jb + 2) * 1024 + nt * 16 + lr] = s2;
            if (jb + 3 < 50) xwp[(ro + jb + 3) * 1024 + nt * 16 + lr] = s3;
          }
        }
      }
    }
  }
}

// ---------------- mainX: 50 steps, 4 batches/block, xw table, 16 waves --------
// r9 structure + (a) sched_group_barrier batching of the 16 weight loads per
// tile (16 outstanding 1KB loads/wave amortize L2 latency), (b) xw gather
// prefetched to step top so its HBM latency hides under phase A.
__global__ __launch_bounds__(1024)
__attribute__((amdgpu_waves_per_eu(4, 4)))
void mainX(const void* targets, const void* h0, const void* c0, const void* vt,
           float* ws, void* outp) {
  __shared__ __align__(16) unsigned short hS[16][264];  // 0-3 hi, 4-7 lo, 8-15 zero
  __shared__ float cT[4][256];
  __shared__ float gsh[4][1024];
  __shared__ float bias_s[1024];
  __shared__ float b2s[4][64];
  __shared__ float outs[4][64];
  __shared__ float vt_s[64];
  __shared__ int   selidx[4];
  __shared__ int   selb[4][64];

  const int b16 = ((const int*)ws)[0];
  const int t = threadIdx.x;
  const int bbase = blockIdx.x * 4;
  const unsigned short* wb = (const unsigned short*)(ws + O_WB);
  const float* xw = ws + O_XW;

  bias_s[t & 1023] = ws[O_BIAS + (t & 1023)];
  if (t < 64) vt_s[t] = ldv(vt, b16, t);
  if (t < 256) selb[t >> 6][t & 63] = 0;
  if (t < 4) selidx[t] = -1;
  {
    unsigned short* z1 = &hS[0][0];
    for (int k = t; k < 16 * 264; k += 1024) z1[k] = 0;
  }
  __syncthreads();
  {
    int p = t >> 8, j = t & 255;
    float h = ldv(h0, b16, (long long)(bbase + p) * 256 + j);
    float c = ldv(c0, b16, (long long)(bbase + p) * 256 + j);
    unsigned short hi = f2b(h);
    hS[p][j]     = hi;
    hS[p + 4][j] = f2b(h - b2f((unsigned int)hi));
    cT[p][j]     = c;
  }
  __syncthreads();

  const int l  = t & 63, Wv = t >> 6;   // lane, wave (0..15)
  const int lr = l & 15, hc = l >> 4;
  const int pj_j = t & 255, pj_p = t >> 8;   // this thread's (batch, gate-j) for A2

  #pragma unroll 1
  for (int step = 0; step < 50; ++step) {
    // ---- xw prefetch for A2 (issued before phase A; HBM latency hides) ----
    float xg0 = 0.f, xg1 = 0.f, xg2 = 0.f, xg3 = 0.f;
    {
      int sv = selidx[pj_p];
      if (sv >= 0) {
        const float* xr = xw + ((long long)(bbase + pj_p) * 50 + sv) * 1024;
        xg0 = xr[pj_j]; xg1 = xr[256 + pj_j];
        xg2 = xr[512 + pj_j]; xg3 = xr[768 + pj_j];
      }
    }

    // ---- phase A: gsh[p][g] = h@W_hh^T (4 tiles/wave, 16 loads + 16 MFMAs) ----
    {
      bf16x8 ah[8];
      #pragma unroll
      for (int kc = 0; kc < 8; ++kc)
        ah[kc] = *(const bf16x8*)&hS[lr][kc * 32 + hc * 8];
      #pragma unroll 1
      for (int ti = 0; ti < 4; ++ti) {
        const int nt = Wv * 4 + ti;
        const unsigned short* tb = wb + (long long)nt * WB_TILE + l * 8;
        bf16x8 w[16];
        #pragma unroll
        for (int kc = 0; kc < 8; ++kc) {
          w[kc]     = *(const bf16x8*)(tb + kc * 512);
          w[8 + kc] = *(const bf16x8*)(tb + 4096 + kc * 512);
        }
        f32x4 aH = {0.f,0.f,0.f,0.f}, aL = {0.f,0.f,0.f,0.f};
        #pragma unroll
        for (int kc = 0; kc < 8; ++kc) {
          aH = mfma16(ah[kc], w[kc], aH);
          aL = mfma16(ah[kc], w[8 + kc], aL);
        }
        __builtin_amdgcn_sched_group_barrier(0x020, 16, 0); // 16 VMEM_READ first
        __builtin_amdgcn_sched_group_barrier(0x008, 16, 0); // then 16 MFMA
        f32x4 acc = aH + aL;
        // rows 0-3 (hi, lanes 0-15) + rows 4-7 (lo, lanes 16-31)
        float s0 = acc[0] + __shfl_xor(acc[0], 16, 64);
        float s1 = acc[1] + __shfl_xor(acc[1], 16, 64);
        float s2 = acc[2] + __shfl_xor(acc[2], 16, 64);
        float s3 = acc[3] + __shfl_xor(acc[3], 16, 64);
        if (l < 16) {
          const int g = nt * 16 + l;
          gsh[0][g] = s0; gsh[1][g] = s1; gsh[2][g] = s2; gsh[3][g] = s3;
        }
      }
    }
    __syncthreads();

    // ---- phase A2: add prefetched xw + bias, LSTM pointwise; h -> hi/lo ----
    {
      int j = pj_j, p = pj_p;
      float gi = sigm (gsh[p][j]       + xg0 + bias_s[j]);
      float gf = sigm (gsh[p][256 + j] + xg1 + bias_s[256 + j]);
      float gg = tanhx(gsh[p][512 + j] + xg2 + bias_s[512 + j]);
      float go = sigm (gsh[p][768 + j] + xg3 + bias_s[768 + j]);
      float c = gf * cT[p][j] + gi * gg;
      cT[p][j] = c;
      float h = go * tanhx(c);
      unsigned short hi = f2b(h);
      hS[p][j]     = hi;
      hS[p + 4][j] = f2b(h - b2f((unsigned int)hi));
    }
    __syncthreads();

    // ---- mini-pass: blend2 = h @ W2^T (waves 0-3, 1 tile each) ----
    if (Wv < 4) {
      bf16x8 bh[8];
      #pragma unroll
      for (int kc = 0; kc < 8; ++kc)
        bh[kc] = *(const bf16x8*)&hS[lr][kc * 32 + hc * 8];
      const unsigned short* tb2 = wb + WB_W2 + Wv * 8192 + l * 8;
      f32x4 cH = {0.f,0.f,0.f,0.f}, cL = {0.f,0.f,0.f,0.f};
      #pragma unroll
      for (int kc = 0; kc < 8; ++kc) {
        cH = mfma16(bh[kc], *(const bf16x8*)(tb2 + kc * 512), cH);
        cL = mfma16(bh[kc], *(const bf16x8*)(tb2 + 4096 + kc * 512), cL);
      }
      f32x4 acc = cH + cL;
      float s0 = acc[0] + __shfl_xor(acc[0], 16, 64);
      float s1 = acc[1] + __shfl_xor(acc[1], 16, 64);
      float s2 = acc[2] + __shfl_xor(acc[2], 16, 64);
      float s3 = acc[3] + __shfl_xor(acc[3], 16, 64);
      if (l < 16) {
        const int g = Wv * 16 + l;
        b2s[0][g] = s0; b2s[1][g] = s1; b2s[2][g] = s2; b2s[3][g] = s3;
      }
    }
    __syncthreads();

    // ---- phase C: out = vt . tanh(blend1 + blend2), mask (200 rows x 4 thr) ----
    if (t < 800) {
      int o = t >> 2, q = t & 3;
      int p = o / 50, j = o - p * 50;
      const float* bl = ws + O_BLEND1 + (((long long)(bbase + p) * 50 + j) * 64) + q * 16;
      float acc = 0.f;
      #pragma unroll
      for (int v4 = 0; v4 < 4; ++v4) {
        float4 bv = *(const float4*)(bl + v4 * 4);
        int w0 = q * 16 + v4 * 4;
        acc += vt_s[w0 + 0] * tanhx(bv.x + b2s[p][w0 + 0]);
        acc += vt_s[w0 + 1] * tanhx(bv.y + b2s[p][w0 + 1]);
        acc += vt_s[w0 + 2] * tanhx(bv.z + b2s[p][w0 + 2]);
        acc += vt_s[w0 + 3] * tanhx(bv.w + b2s[p][w0 + 3]);
      }
      acc += __shfl_xor(acc, 1, 64);
      acc += __shfl_xor(acc, 2, 64);
      if (q == 0) outs[p][j] = selb[p][j] ? NEG_INF_V : acc;
    }
    __syncthreads();

    // ---- argmax + softmax + probs (waves 0-3, one batch each) ----
    if (Wv < 4) {
      int p = Wv, lane = l;
      float v = (lane < 50) ? outs[p][lane] : -3.4e38f;
      int idx = lane;
      #pragma unroll
      for (int msk = 1; msk < 64; msk <<= 1) {
        float ov = __shfl_xor(v, msk, 64);
        int   oi = __shfl_xor(idx, msk, 64);
        if (ov > v || (ov == v && oi < idx)) { v = ov; idx = oi; }
      }
      float e = (lane < 50) ? __expf(outs[p][lane] - v) : 0.f;
      float ssum = e;
      #pragma unroll
      for (int msk = 1; msk < 64; msk <<= 1) ssum += __shfl_xor(ssum, msk, 64);
      if (lane < 50) {
        float prob = fmaxf(e / ssum, 1e-9f);
        long long o = (long long)(bbase + p) * 2500 + step * 50 + lane;
        if (b16) ((unsigned short*)outp)[o] = f2b(prob);
        else     ((float*)outp)[o] = prob;
      }
      if (lane == 0) selidx[p] = idx;
      if (lane == idx) selb[p][idx] = 1;
    }
    __syncthreads();
  }
}

// ---------------- mainK6: fallback (round-6-proven, no xw table) ----------------
__global__ __launch_bounds__(512)
__attribute__((amdgpu_waves_per_eu(2, 2)))
void mainK6(const void* targets, const void* h0, const void* c0, const void* vt,
            float* ws, void* outp) {
  __shared__ __align__(16) unsigned short hS[16][264];
  __shared__ __align__(16) unsigned short xA[16][136];
  __shared__ float cT[8][256];
  __shared__ float gsh[8][1024];
  __shared__ float bias_s[1024];
  __shared__ float b2s[8][64];
  __shared__ float outs[8][64];
  __shared__ float vt_s[64];
  __shared__ int   selidx[8];
  __shared__ int   selb[8][64];

  const int b16 = ((const int*)ws)[0];
  const int t = threadIdx.x;
  const int bbase = blockIdx.x * 8;
  const unsigned short* wb = (const unsigned short*)(ws + O_WB);

  for (int k = t; k < 1024; k += 512) bias_s[k] = ws[O_BIAS + k];
  if (t < 64) vt_s[t] = ldv(vt, b16, t);
  if (t < 512) selb[t >> 6][t & 63] = 0;
  if (t < 8) selidx[t] = -1;
  {
    unsigned short* z1 = &hS[0][0];
    unsigned short* z2 = &xA[0][0];
    for (int k = t; k < 16 * 264; k += 512) z1[k] = 0;
    for (int k = t; k < 16 * 136; k += 512) z2[k] = 0;
  }
  __syncthreads();
  for (int k = t; k < 2048; k += 512) {
    int p = k >> 8, j = k & 255;
    float h = ldv(h0, b16, (long long)(bbase + p) * 256 + j);
    float c = ldv(c0, b16, (long long)(bbase + p) * 256 + j);
    unsigned short hi = f2b(h);
    hS[p][j]     = hi;
    hS[p + 8][j] = f2b(h - b2f((unsigned int)hi));
    cT[p][j]     = c;
  }
  __syncthreads();

  const int l  = t & 63, Wv = t >> 6;
  const int lr = l & 15;

  #pragma unroll 1
  for (int step = 0; step < 50; ++step) {
    {
      bf16x8 ah[8], ax[4];
      #pragma unroll
      for (int kc = 0; kc < 8; ++kc)
        ah[kc] = *(const bf16x8*)&hS[lr][kc * 32 + (l >> 4) * 8];
      #pragma unroll
      for (int kc = 0; kc < 4; ++kc)
        ax[kc] = *(const bf16x8*)&xA[lr][kc * 32 + (l >> 4) * 8];
      #pragma unroll 1
      for (int ti = 0; ti < 8; ++ti) {
        const int nt = Wv * 8 + ti;
        const unsigned short* tb = wb + (long long)nt * WB_TILE + l * 8;
        bf16x8 wH[12], wL[12];
        #pragma unroll
        for (int kc = 0; kc < 8; ++kc) {
          wH[kc] = *(const bf16x8*)(tb + kc * 512);
          wL[kc] = *(const bf16x8*)(tb + 4096 + kc * 512);
        }
        #pragma unroll
        for (int kc = 0; kc < 4; ++kc) {
          wH[8 + kc] = *(const bf16x8*)(tb + 8192 + kc * 512);
          wL[8 + kc] = *(const bf16x8*)(tb + 10240 + kc * 512);
        }
        f32x4 aH = {0.f,0.f,0.f,0.f}, aL = {0.f,0.f,0.f,0.f};
        #pragma unroll
        for (int kc = 0; kc < 8; ++kc) {
          aH = mfma16(ah[kc], wH[kc], aH);
          aL = mfma16(ah[kc], wL[kc], aL);
        }
        #pragma unroll
        for (int kc = 0; kc < 4; ++kc) {
          aH = mfma16(ax[kc], wH[8 + kc], aH);
          aL = mfma16(ax[kc], wL[8 + kc], aL);
        }
        f32x4 acc = aH + aL;
        float s0 = acc[0] + __shfl_xor(acc[0], 32, 64);
        float s1 = acc[1] + __shfl_xor(acc[1], 32, 64);
        float s2 = acc[2] + __shfl_xor(acc[2], 32, 64);
        float s3 = acc[3] + __shfl_xor(acc[3], 32, 64);
        if (l < 32) {
          const int g = nt * 16 + (l & 15), pb = (l >> 4) * 4;
          gsh[pb + 0][g] = s0; gsh[pb + 1][g] = s1;
          gsh[pb + 2][g] = s2; gsh[pb + 3][g] = s3;
        }
      }
    }
    __syncthreads();

    for (int k = t; k < 2048; k += 512) {
      int j = k & 255, p = k >> 8;
      float gi = sigm (gsh[p][j]       + bias_s[j]);
      float gf = sigm (gsh[p][256 + j] + bias_s[256 + j]);
      float gg = tanhx(gsh[p][512 + j] + bias_s[512 + j]);
      float go = sigm (gsh[p][768 + j] + bias_s[768 + j]);
      float c = gf * cT[p][j] + gi * gg;
      cT[p][j] = c;
      float h = go * tanhx(c);
      unsigned short hi = f2b(h);
      hS[p][j]     = hi;
      hS[p + 8][j] = f2b(h - b2f((unsigned int)hi));
    }
    __syncthreads();

    if (Wv < 4) {
      bf16x8 bh[8];
      #pragma unroll
      for (int kc = 0; kc < 8; ++kc)
        bh[kc] = *(const bf16x8*)&hS[lr][kc * 32 + (l >> 4) * 8];
      const unsigned short* tb = wb + WB_W2 + Wv * 8192 + l * 8;
      f32x4 aH = {0.f,0.f,0.f,0.f}, aL = {0.f,0.f,0.f,0.f};
      #pragma unroll
      for (int kc = 0; kc < 8; ++kc) {
        aH = mfma16(bh[kc], *(const bf16x8*)(tb + kc * 512), aH);
        aL = mfma16(bh[kc], *(const bf16x8*)(tb + 4096 + kc * 512), aL);
      }
      f32x4 acc = aH + aL;
      float s0 = acc[0] + __shfl_xor(acc[0], 32, 64);
      float s1 = acc[1] + __shfl_xor(acc[1], 32, 64);
      float s2 = acc[2] + __shfl_xor(acc[2], 32, 64);
      float s3 = acc[3] + __shfl_xor(acc[3], 32, 64);
      if (l < 32) {
        const int g = Wv * 16 + (l & 15), pb = (l >> 4) * 4;
        b2s[pb + 0][g] = s0; b2s[pb + 1][g] = s1;
        b2s[pb + 2][g] = s2; b2s[pb + 3][g] = s3;
      }
    }
    __syncthreads();

    if (t < 400) {
      int p = t / 50, j = t - p * 50;
      const float* bl = ws + O_BLEND1 + (((bbase + p) * 50 + j) * 64);
      float acc = 0.f;
      #pragma unroll
      for (int v4 = 0; v4 < 16; ++v4) {
        float4 bv = *(const float4*)(bl + v4 * 4);
        int w0 = v4 * 4;
        acc += vt_s[w0 + 0] * tanhx(bv.x + b2s[p][w0 + 0]);
        acc += vt_s[w0 + 1] * tanhx(bv.y + b2s[p][w0 + 1]);
        acc += vt_s[w0 + 2] * tanhx(bv.z + b2s[p][w0 + 2]);
        acc += vt_s[w0 + 3] * tanhx(bv.w + b2s[p][w0 + 3]);
      }
      outs[p][j] = selb[p][j] ? NEG_INF_V : acc;
    }
    __syncthreads();

    {
      int p = Wv, lane = l;
      float v = (lane < 50) ? outs[p][lane] : -3.4e38f;
      int idx = lane;
      #pragma unroll
      for (int msk = 1; msk < 64; msk <<= 1) {
        float ov = __shfl_xor(v, msk, 64);
        int   oi = __shfl_xor(idx, msk, 64);
        if (ov > v || (ov == v && oi < idx)) { v = ov; idx = oi; }
      }
      float e = (lane < 50) ? __expf(outs[p][lane] - v) : 0.f;
      float ssum = e;
      #pragma unroll
      for (int msk = 1; msk < 64; msk <<= 1) ssum += __shfl_xor(ssum, msk, 64);
      if (lane < 50) {
        float prob = fmaxf(e / ssum, 1e-9f);
        int o = (bbase + p) * 2500 + step * 50 + lane;
        if (b16) ((unsigned short*)outp)[o] = f2b(prob);
        else     ((float*)outp)[o] = prob;
      }
      if (lane == 0) selidx[p] = idx;
      if (lane == idx) selb[p][idx] = 1;
    }
    __syncthreads();

    for (int k = t; k < 1024; k += 512) {
      int p = k >> 7, i = k & 127;
      float xf = ldv(targets, b16,
                     ((long long)(bbase + p) * 50 + selidx[p]) * 128 + i);
      unsigned short hi = f2b(xf);
      xA[p][i]     = hi;
      xA[p + 8][i] = f2b(xf - b2f((unsigned int)hi));
    }
    __syncthreads();
  }
}

extern "C" void kernel_launch(void* const* d_in, const int* in_sizes, int n_in,
                              void* d_out, int out_size, void* d_ws, size_t ws_size,
                              hipStream_t stream) {
  (void)in_sizes; (void)n_in; (void)out_size;
  const void* targets = d_in[0];
  const void* h0      = d_in[1];
  const void* c0      = d_in[2];
  const void* W_enc   = d_in[3];
  const void* b_enc   = d_in[4];
  const void* W_ih    = d_in[5];
  const void* W_hh    = d_in[6];
  const void* b_ih    = d_in[7];
  const void* b_hh    = d_in[8];
  const void* W1      = d_in[9];
  const void* W2      = d_in[10];
  const void* vt      = d_in[11];
  float* ws = (float*)d_ws;

  int use_xw = (ws_size >= ((size_t)O_XW + (size_t)XW_FLOATS) * 4) ? 1 : 0;

  prep0<<<1, 256, 0, stream>>>(b_enc, b_ih, b_hh, W1, ws);
  prep1<<<32, 256, 0, stream>>>(W_enc, W1, ws);
  wprep<<<1024, 256, 0, stream>>>(W_ih, W_hh, W2, ws);
  blendk<<<1024, 256, 0, stream>>>(targets, ws);
  if (use_xw) {
    xwK<<<256, 512, 0, stream>>>(targets, ws);
    mainX<<<256, 1024, 0, stream>>>(targets, h0, c0, vt, ws, d_out);
  } else {
    mainK6<<<128, 512, 0, stream>>>(targets, h0, c0, vt, ws, d_out);
  }
}

// Round 11
// 991.823 us; speedup vs baseline: 1.2632x; 1.2632x over previous
//
#include <hip/hip_runtime.h>

// ---------------- ws layout (float offsets) ----------------
#define O_WC     16
#define O_BC     (16 + 8192)
#define O_BIAS   (O_BC + 64)
#define O_BLEND1 16384
#define O_WB     3293184        // packed hi/lo weights (ushort region), 409600 floats
#define O_XW     4194304        // xw table [1024][50][1024] fp32 (use_xw only)
#define XW_FLOATS 52428800ULL
#define NEG_INF_V (-1.0e9f)

// packed weight region (ushort offsets). Gate tile nt (0..63) stride WB_TILE:
//   [0,4096) hhH kc*512+lane*8+e | [4096,8192) hhL
//   [8192,10240) ihH kc*512+lane*8+e | [10240,12288) ihL
// W2 tile ntw (0..3) at WB_W2 + ntw*8192: [0,4096) hi, [4096,8192) lo.
#define WB_TILE 12288
#define WB_W2   786432

using bf16x8 = __attribute__((ext_vector_type(8))) __bf16;
using f32x4  = __attribute__((ext_vector_type(4))) float;

__device__ __forceinline__ f32x4 mfma16(bf16x8 a, bf16x8 b, f32x4 c) {
  return __builtin_amdgcn_mfma_f32_16x16x32_bf16(a, b, c, 0, 0, 0);
}

__device__ __forceinline__ float b2f(unsigned int u) {
  union { unsigned int i; float f; } x; x.i = u << 16; return x.f;
}
__device__ __forceinline__ unsigned short f2b(float f) {
  union { float f; unsigned int i; } x; x.f = f;
  unsigned int r = x.i + 0x7fffu + ((x.i >> 16) & 1u);
  return (unsigned short)(r >> 16);
}
__device__ __forceinline__ float ldv(const void* p, int b16, long long i) {
  if (b16) return b2f(((const unsigned short*)p)[i]);
  return ((const float*)p)[i];
}
__device__ __forceinline__ float sigm(float x)  { return 1.0f / (1.0f + __expf(-x)); }
__device__ __forceinline__ float tanhx(float x) { return 1.0f - 2.0f / (1.0f + __expf(2.0f * x)); }

__device__ __forceinline__ float bfsel(const uint4& u, int e) {
  unsigned int w = (e < 2) ? u.x : (e < 4) ? u.y : (e < 6) ? u.z : u.w;
  union { unsigned int i; float f; } x;
  x.i = (e & 1) ? (w & 0xffff0000u) : (w << 16);
  return x.f;
}

// ---------------- prepAll: fused prep0 + prep1 + wprep ----------------
// Each block derives the dtype flag locally from b_enc (256 values, cheap),
// so no cross-kernel dependency; block 0 also writes flag/bias/bc, blocks
// 0-31 compute Wc, all 1024 blocks do the hi/lo weight decomposition.
__global__ __launch_bounds__(256) void prepAll(
    const void* b_enc, const void* b_ih, const void* b_hh, const void* W1,
    const void* W_ih, const void* W_hh, const void* W2, float* ws) {
  __shared__ int anybig;
  const int t = threadIdx.x;
  const int blk = blockIdx.x;
  if (t == 0) anybig = 0;
  __syncthreads();
  {
    unsigned short u = ((const unsigned short*)b_enc)[t];
    float f = b2f((unsigned int)u);
    if (!(fabsf(f) <= 1.0f)) atomicOr(&anybig, 1);
  }
  __syncthreads();
  const int b16 = anybig ? 0 : 1;

  if (blk == 0) {
    if (t == 0) ((int*)ws)[0] = b16;
    for (int k = t; k < 1024; k += 256)
      ws[O_BIAS + k] = ldv(b_ih, b16, k) + ldv(b_hh, b16, k);
    if (t < 64) {
      float acc = 0.f;
      for (int h = 0; h < 256; ++h)
        acc += ldv(W1, b16, t * 256 + h) * ldv(b_enc, b16, h);
      ws[O_BC + t] = acc;
    }
  }
  if (blk < 32) {   // prep1: Wc = W1 @ W_enc handled via W1/W_enc — W_enc passed as b_hh? no:
  }
  // (prep1 done below with explicit args)
  unsigned short* wb = (unsigned short*)(ws + O_WB);
  const int i = blk * 256 + t;   // 0..262143
  {  // W_hh [1024][256]
    int g = i >> 8, k = i & 255;
    int nt = g >> 4, r = g & 15;
    int kc = k >> 5, lane = ((k >> 3) & 3) * 16 + r, e = k & 7;
    float w = ldv(W_hh, b16, i);
    unsigned short hi = f2b(w);
    long long d = (long long)nt * WB_TILE + kc * 512 + lane * 8 + e;
    wb[d] = hi;
    wb[d + 4096] = f2b(w - b2f((unsigned int)hi));
  }
  if (i < 131072) {  // W_ih [1024][128]
    int g = i >> 7, k = i & 127;
    int nt = g >> 4, r = g & 15;
    int kc = k >> 5, lane = ((k >> 3) & 3) * 16 + r, e = k & 7;
    float w = ldv(W_ih, b16, i);
    unsigned short hi = f2b(w);
    long long d = (long long)nt * WB_TILE + 8192 + kc * 512 + lane * 8 + e;
    wb[d] = hi;
    wb[d + 2048] = f2b(w - b2f((unsigned int)hi));
  }
  if (i < 16384) {   // W2 [64][256]
    int g = i >> 8, k = i & 255;
    int ntw = g >> 4, r = g & 15;
    int kc = k >> 5, lane = ((k >> 3) & 3) * 16 + r, e = k & 7;
    float w = ldv(W2, b16, i);
    unsigned short hi = f2b(w);
    long long d = WB_W2 + ntw * 8192 + kc * 512 + lane * 8 + e;
    wb[d] = hi;
    wb[d + 4096] = f2b(w - b2f((unsigned int)hi));
  }
}

// ---------------- prep1: Wc = W1 @ W_enc (kept separate: needs W_enc) -------
__global__ void prep1(const void* W_enc, const void* W1, const void* b_enc,
                      float* ws) {
  __shared__ int anybig;
  int t = threadIdx.x;
  if (t == 0) anybig = 0;
  __syncthreads();
  {
    unsigned short u = ((const unsigned short*)b_enc)[t];
    float f = b2f((unsigned int)u);
    if (!(fabsf(f) <= 1.0f)) atomicOr(&anybig, 1);
  }
  __syncthreads();
  int b16 = anybig ? 0 : 1;
  int o = blockIdx.x * 256 + t;
  int w = o >> 7, i = o & 127;
  float acc = 0.f;
  for (int h = 0; h < 256; ++h)
    acc += ldv(W1, b16, w * 256 + h) * ldv(W_enc, b16, h * 128 + i);
  ws[O_WC + o] = acc;
}

// ---------------- blendk: blend1 = targets @ Wc^T + bc ----------------
__global__ __launch_bounds__(256) void blendk(const void* targets, float* ws) {
  __shared__ float tg[6400];
  __shared__ float wc[8192];
  int b16 = ((const int*)ws)[0];
  int t = threadIdx.x, b = blockIdx.x;
  for (int k = t; k < 8192; k += 256) wc[k] = ws[O_WC + k];
  if (b16) {
    const unsigned short* tp = (const unsigned short*)targets + (long long)b * 6400;
    for (int k = t * 8; k < 6400; k += 2048) {
      uint4 u = *(const uint4*)(tp + k);
      #pragma unroll
      for (int e = 0; e < 8; ++e) tg[k + e] = bfsel(u, e);
    }
  } else {
    const float* tp = (const float*)targets + (long long)b * 6400;
    for (int k = t; k < 6400; k += 256) tg[k] = tp[k];
  }
  __syncthreads();
  int w = t & 63, j0 = t >> 6;
  float bcv = ws[O_BC + w];
  for (int j = j0; j < 50; j += 4) {
    float acc = 0.f;
    for (int i0 = 0; i0 < 128; i0 += 8) {
      const float4* q = (const float4*)(wc + w * 128 + i0);
      float4 a = q[0], bb = q[1];
      const float* x = &tg[j * 128 + i0];
      acc += a.x * x[0] + a.y * x[1] + a.z * x[2] + a.w * x[3]
           + bb.x * x[4] + bb.y * x[5] + bb.z * x[6] + bb.w * x[7];
    }
    ws[O_BLEND1 + (b * 50 + j) * 64 + w] = acc + bcv;
  }
}

// ---------------- xwK: xw[b][j][g] = targets[b,j,:].W_ih[g,:] (hi/lo MFMA) ----
__global__ __launch_bounds__(512)
__attribute__((amdgpu_waves_per_eu(2, 2)))
void xwK(const void* targets, float* ws) {
  __shared__ __align__(16) unsigned short tgS[4][32][264]; // hi 0-127, lo 128-255
  const int b16 = ((const int*)ws)[0];
  const int t = threadIdx.x;
  const int b0 = blockIdx.x * 4;
  const unsigned short* wb = (const unsigned short*)(ws + O_WB);
  float* xwp = ws + O_XW;
  const int l = t & 63, Wv = t >> 6, lr = l & 15, hc = l >> 4;

  #pragma unroll 1
  for (int half = 0; half < 2; ++half) {
    __syncthreads();
    for (int k = t; k < 4 * 32 * 128; k += 512) {
      int p = k >> 12, jr = (k >> 7) & 31, i = k & 127;
      int j = half * 32 + jr;
      float v = (j < 50) ? ldv(targets, b16, ((long long)(b0 + p) * 50 + j) * 128 + i)
                         : 0.f;
      unsigned short hi = f2b(v);
      tgS[p][jr][i]       = hi;
      tgS[p][jr][128 + i] = f2b(v - b2f((unsigned int)hi));
    }
    __syncthreads();
    const int njg = (half == 0) ? 4 : 3;
    #pragma unroll 1
    for (int ti = 0; ti < 8; ++ti) {
      const int nt = Wv * 8 + ti;
      const unsigned short* tb = wb + (long long)nt * WB_TILE + 8192 + l * 8;
      bf16x8 wih[8];
      #pragma unroll
      for (int kc = 0; kc < 4; ++kc) {
        wih[kc]     = *(const bf16x8*)(tb + kc * 512);
        wih[4 + kc] = *(const bf16x8*)(tb + 2048 + kc * 512);
      }
      #pragma unroll 1
      for (int p = 0; p < 4; ++p) {
        #pragma unroll 1
        for (int jh = 0; jh < njg; ++jh) {
          bf16x8 ax[4];
          const unsigned short* tp =
              &tgS[p][jh * 8 + (lr & 7)][((lr < 8) ? 0 : 128) + hc * 8];
          #pragma unroll
          for (int kc = 0; kc < 4; ++kc) ax[kc] = *(const bf16x8*)(tp + kc * 32);
          f32x4 cH = {0.f,0.f,0.f,0.f}, cL = {0.f,0.f,0.f,0.f};
          #pragma unroll
          for (int kc = 0; kc < 4; ++kc) {
            cH = mfma16(ax[kc], wih[kc], cH);
            cL = mfma16(ax[kc], wih[4 + kc], cL);
          }
          f32x4 acc = cH + cL;
          float s0 = acc[0] + __shfl_xor(acc[0], 32, 64);
          float s1 = acc[1] + __shfl_xor(acc[1], 32, 64);
          float s2 = acc[2] + __shfl_xor(acc[2], 32, 64);
          float s3 = acc[3] + __shfl_xor(acc[3], 32, 64);
          if (l < 32) {
            int jb = half * 32 + jh * 8 + hc * 4;
            long long ro = (long long)(b0 + p) * 50;
            if (jb + 0 < 50) xwp[(ro + jb + 0) * 1024 + nt * 16 + lr] = s0;
            if (jb + 1 < 50) xwp[(ro + jb + 1) * 1024 + nt * 16 + lr] = s1;
            if (jb + 2 < 50) xwp[(ro + jb + 2) * 1024 + nt * 16 + lr] = s2;
            if (jb + 3 < 50) xwp[(ro + jb + 3) * 1024 + nt * 16 + lr] = s3;
          }
        }
      }
    }
  }
}

// ---------------- mainX: r9 base + depth-4 load pipeline + reg-blend1 + xw->LDS
__global__ __launch_bounds__(1024)
__attribute__((amdgpu_waves_per_eu(4, 4)))
void mainX(const void* targets, const void* h0, const void* c0, const void* vt,
           float* ws, void* outp) {
  __shared__ __align__(16) unsigned short hS[16][264];  // 0-3 hi, 4-7 lo, 8-15 zero
  __shared__ __align__(16) float xwS[4][1024];          // prefetched xw rows
  __shared__ float cT[4][256];
  __shared__ float gsh[4][1024];
  __shared__ float bias_s[1024];
  __shared__ float b2s[4][64];
  __shared__ float outs[4][64];
  __shared__ float vt_s[64];
  __shared__ int   selidx[4];
  __shared__ int   selb[4][64];

  const int b16 = ((const int*)ws)[0];
  const int t = threadIdx.x;
  const int bbase = blockIdx.x * 4;
  const unsigned short* wb = (const unsigned short*)(ws + O_WB);
  const float* xw = ws + O_XW;

  bias_s[t & 1023] = ws[O_BIAS + (t & 1023)];
  if (t < 64) vt_s[t] = ldv(vt, b16, t);
  if (t < 256) selb[t >> 6][t & 63] = 0;
  if (t < 4) selidx[t] = -1;
  {
    unsigned short* z1 = &hS[0][0];
    for (int k = t; k < 16 * 264; k += 1024) z1[k] = 0;
  }
  __syncthreads();
  {
    int p = t >> 8, j = t & 255;
    float h = ldv(h0, b16, (long long)(bbase + p) * 256 + j);
    float c = ldv(c0, b16, (long long)(bbase + p) * 256 + j);
    unsigned short hi = f2b(h);
    hS[p][j]     = hi;
    hS[p + 4][j] = f2b(h - b2f((unsigned int)hi));
    cT[p][j]     = c;
  }
  __syncthreads();

  const int l  = t & 63, Wv = t >> 6;   // lane, wave (0..15)
  const int lr = l & 15, hc = l >> 4;

  // ---- step-invariant blend1 slice -> registers (16 floats, loaded once) ----
  float bl1[16];
  int cp = 0, cj = 0, cq = 0;
  if (t < 800) {
    int o = t >> 2; cq = t & 3;
    cp = o / 50; cj = o - cp * 50;
    const float* bl = ws + O_BLEND1 + (((long long)(bbase + cp) * 50 + cj) * 64) + cq * 16;
    #pragma unroll
    for (int v4 = 0; v4 < 4; ++v4) {
      float4 bv = *(const float4*)(bl + v4 * 4);
      bl1[v4 * 4 + 0] = bv.x; bl1[v4 * 4 + 1] = bv.y;
      bl1[v4 * 4 + 2] = bv.z; bl1[v4 * 4 + 3] = bv.w;
    }
  } else {
    #pragma unroll
    for (int e = 0; e < 16; ++e) bl1[e] = 0.f;
  }

  #pragma unroll 1
  for (int step = 0; step < 50; ++step) {
    // ---- phase A: gsh[p][g] = h@W_hh^T, depth-4 rolling load pipeline ----
    {
      bf16x8 ah[8];
      #pragma unroll
      for (int kc = 0; kc < 8; ++kc)
        ah[kc] = *(const bf16x8*)&hS[lr][kc * 32 + hc * 8];
      #pragma unroll 1
      for (int ti = 0; ti < 4; ++ti) {
        const int nt = Wv * 4 + ti;
        const unsigned short* tb = wb + (long long)nt * WB_TILE + l * 8;
        bf16x8 wh[4], wl[4];
        #pragma unroll
        for (int q2 = 0; q2 < 4; ++q2) {
          wh[q2] = *(const bf16x8*)(tb + q2 * 512);
          wl[q2] = *(const bf16x8*)(tb + 4096 + q2 * 512);
        }
        f32x4 aH = {0.f,0.f,0.f,0.f}, aL = {0.f,0.f,0.f,0.f};
        #pragma unroll
        for (int kc = 0; kc < 8; ++kc) {
          const int cur = kc & 3;
          aH = mfma16(ah[kc], wh[cur], aH);
          aL = mfma16(ah[kc], wl[cur], aL);
          if (kc + 4 < 8) {
            wh[cur] = *(const bf16x8*)(tb + (kc + 4) * 512);
            wl[cur] = *(const bf16x8*)(tb + 4096 + (kc + 4) * 512);
          }
        }
        f32x4 acc = aH + aL;
        // rows 0-3 (hi, lanes 0-15) + rows 4-7 (lo, lanes 16-31)
        float s0 = acc[0] + __shfl_xor(acc[0], 16, 64);
        float s1 = acc[1] + __shfl_xor(acc[1], 16, 64);
        float s2 = acc[2] + __shfl_xor(acc[2], 16, 64);
        float s3 = acc[3] + __shfl_xor(acc[3], 16, 64);
        if (l < 16) {
          const int g = nt * 16 + l;
          gsh[0][g] = s0; gsh[1][g] = s1; gsh[2][g] = s2; gsh[3][g] = s3;
        }
      }
    }
    __syncthreads();

    // ---- phase A2: add prefetched xw (LDS) + bias, LSTM pointwise ----
    {
      int j = t & 255, p = t >> 8;
      float gi = gsh[p][j], gf = gsh[p][256 + j];
      float gg = gsh[p][512 + j], go = gsh[p][768 + j];
      if (selidx[p] >= 0) {
        gi += xwS[p][j]; gf += xwS[p][256 + j];
        gg += xwS[p][512 + j]; go += xwS[p][768 + j];
      }
      gi = sigm (gi + bias_s[j]);
      gf = sigm (gf + bias_s[256 + j]);
      gg = tanhx(gg + bias_s[512 + j]);
      go = sigm (go + bias_s[768 + j]);
      float c = gf * cT[p][j] + gi * gg;
      cT[p][j] = c;
      float h = go * tanhx(c);
      unsigned short hi = f2b(h);
      hS[p][j]     = hi;
      hS[p + 4][j] = f2b(h - b2f((unsigned int)hi));
    }
    __syncthreads();

    // ---- mini-pass: blend2 = h @ W2^T (waves 0-3, 1 tile each) ----
    if (Wv < 4) {
      bf16x8 bh[8];
      #pragma unroll
      for (int kc = 0; kc < 8; ++kc)
        bh[kc] = *(const bf16x8*)&hS[lr][kc * 32 + hc * 8];
      const unsigned short* tb2 = wb + WB_W2 + Wv * 8192 + l * 8;
      f32x4 cH = {0.f,0.f,0.f,0.f}, cL = {0.f,0.f,0.f,0.f};
      #pragma unroll
      for (int kc = 0; kc < 8; ++kc) {
        cH = mfma16(bh[kc], *(const bf16x8*)(tb2 + kc * 512), cH);
        cL = mfma16(bh[kc], *(const bf16x8*)(tb2 + 4096 + kc * 512), cL);
      }
      f32x4 acc = cH + cL;
      float s0 = acc[0] + __shfl_xor(acc[0], 16, 64);
      float s1 = acc[1] + __shfl_xor(acc[1], 16, 64);
      float s2 = acc[2] + __shfl_xor(acc[2], 16, 64);
      float s3 = acc[3] + __shfl_xor(acc[3], 16, 64);
      if (l < 16) {
        const int g = Wv * 16 + l;
        b2s[0][g] = s0; b2s[1][g] = s1; b2s[2][g] = s2; b2s[3][g] = s3;
      }
    }
    __syncthreads();

    // ---- phase C: out = vt . tanh(blend1(reg) + blend2), mask ----
    if (t < 800) {
      float acc = 0.f;
      #pragma unroll
      for (int e = 0; e < 16; ++e) {
        int w0 = cq * 16 + e;
        acc += vt_s[w0] * tanhx(bl1[e] + b2s[cp][w0]);
      }
      acc += __shfl_xor(acc, 1, 64);
      acc += __shfl_xor(acc, 2, 64);
      if (cq == 0) outs[cp][cj] = selb[cp][cj] ? NEG_INF_V : acc;
    }
    __syncthreads();

    // ---- argmax + softmax + probs + xw-row prefetch (waves 0-3) ----
    if (Wv < 4) {
      int p = Wv, lane = l;
      float v = (lane < 50) ? outs[p][lane] : -3.4e38f;
      int idx = lane;
      #pragma unroll
      for (int msk = 1; msk < 64; msk <<= 1) {
        float ov = __shfl_xor(v, msk, 64);
        int   oi = __shfl_xor(idx, msk, 64);
        if (ov > v || (ov == v && oi < idx)) { v = ov; idx = oi; }
      }
      // prefetch next step's xw row into LDS (idx known in-register)
      {
        const float* xr = xw + ((long long)(bbase + p) * 50 + idx) * 1024;
        #pragma unroll
        for (int kk = 0; kk < 4; ++kk)
          *(float4*)&xwS[p][lane * 4 + kk * 256] =
              *(const float4*)(xr + lane * 4 + kk * 256);
      }
      float e = (lane < 50) ? __expf(outs[p][lane] - v) : 0.f;
      float ssum = e;
      #pragma unroll
      for (int msk = 1; msk < 64; msk <<= 1) ssum += __shfl_xor(ssum, msk, 64);
      if (lane < 50) {
        float prob = fmaxf(e / ssum, 1e-9f);
        long long o = (long long)(bbase + p) * 2500 + step * 50 + lane;
        if (b16) ((unsigned short*)outp)[o] = f2b(prob);
        else     ((float*)outp)[o] = prob;
      }
      if (lane == 0) selidx[p] = idx;
      if (lane == idx) selb[p][idx] = 1;
    }
    __syncthreads();
  }
}

// ---------------- mainK6: fallback (round-6-proven, no xw table) ----------------
__global__ __launch_bounds__(512)
__attribute__((amdgpu_waves_per_eu(2, 2)))
void mainK6(const void* targets, const void* h0, const void* c0, const void* vt,
            float* ws, void* outp) {
  __shared__ __align__(16) unsigned short hS[16][264];
  __shared__ __align__(16) unsigned short xA[16][136];
  __shared__ float cT[8][256];
  __shared__ float gsh[8][1024];
  __shared__ float bias_s[1024];
  __shared__ float b2s[8][64];
  __shared__ float outs[8][64];
  __shared__ float vt_s[64];
  __shared__ int   selidx[8];
  __shared__ int   selb[8][64];

  const int b16 = ((const int*)ws)[0];
  const int t = threadIdx.x;
  const int bbase = blockIdx.x * 8;
  const unsigned short* wb = (const unsigned short*)(ws + O_WB);

  for (int k = t; k < 1024; k += 512) bias_s[k] = ws[O_BIAS + k];
  if (t < 64) vt_s[t] = ldv(vt, b16, t);
  if (t < 512) selb[t >> 6][t & 63] = 0;
  if (t < 8) selidx[t] = -1;
  {
    unsigned short* z1 = &hS[0][0];
    unsigned short* z2 = &xA[0][0];
    for (int k = t; k < 16 * 264; k += 512) z1[k] = 0;
    for (int k = t; k < 16 * 136; k += 512) z2[k] = 0;
  }
  __syncthreads();
  for (int k = t; k < 2048; k += 512) {
    int p = k >> 8, j = k & 255;
    float h = ldv(h0, b16, (long long)(bbase + p) * 256 + j);
    float c = ldv(c0, b16, (long long)(bbase + p) * 256 + j);
    unsigned short hi = f2b(h);
    hS[p][j]     = hi;
    hS[p + 8][j] = f2b(h - b2f((unsigned int)hi));
    cT[p][j]     = c;
  }
  __syncthreads();

  const int l  = t & 63, Wv = t >> 6;
  const int lr = l & 15;

  #pragma unroll 1
  for (int step = 0; step < 50; ++step) {
    {
      bf16x8 ah[8], ax[4];
      #pragma unroll
      for (int kc = 0; kc < 8; ++kc)
        ah[kc] = *(const bf16x8*)&hS[lr][kc * 32 + (l >> 4) * 8];
      #pragma unroll
      for (int kc = 0; kc < 4; ++kc)
        ax[kc] = *(const bf16x8*)&xA[lr][kc * 32 + (l >> 4) * 8];
      #pragma unroll 1
      for (int ti = 0; ti < 8; ++ti) {
        const int nt = Wv * 8 + ti;
        const unsigned short* tb = wb + (long long)nt * WB_TILE + l * 8;
        bf16x8 wH[12], wL[12];
        #pragma unroll
        for (int kc = 0; kc < 8; ++kc) {
          wH[kc] = *(const bf16x8*)(tb + kc * 512);
          wL[kc] = *(const bf16x8*)(tb + 4096 + kc * 512);
        }
        #pragma unroll
        for (int kc = 0; kc < 4; ++kc) {
          wH[8 + kc] = *(const bf16x8*)(tb + 8192 + kc * 512);
          wL[8 + kc] = *(const bf16x8*)(tb + 10240 + kc * 512);
        }
        f32x4 aH = {0.f,0.f,0.f,0.f}, aL = {0.f,0.f,0.f,0.f};
        #pragma unroll
        for (int kc = 0; kc < 8; ++kc) {
          aH = mfma16(ah[kc], wH[kc], aH);
          aL = mfma16(ah[kc], wL[kc], aL);
        }
        #pragma unroll
        for (int kc = 0; kc < 4; ++kc) {
          aH = mfma16(ax[kc], wH[8 + kc], aH);
          aL = mfma16(ax[kc], wL[8 + kc], aL);
        }
        f32x4 acc = aH + aL;
        float s0 = acc[0] + __shfl_xor(acc[0], 32, 64);
        float s1 = acc[1] + __shfl_xor(acc[1], 32, 64);
        float s2 = acc[2] + __shfl_xor(acc[2], 32, 64);
        float s3 = acc[3] + __shfl_xor(acc[3], 32, 64);
        if (l < 32) {
          const int g = nt * 16 + (l & 15), pb = (l >> 4) * 4;
          gsh[pb + 0][g] = s0; gsh[pb + 1][g] = s1;
          gsh[pb + 2][g] = s2; gsh[pb + 3][g] = s3;
        }
      }
    }
    __syncthreads();

    for (int k = t; k < 2048; k += 512) {
      int j = k & 255, p = k >> 8;
      float gi = sigm (gsh[p][j]       + bias_s[j]);
      float gf = sigm (gsh[p][256 + j] + bias_s[256 + j]);
      float gg = tanhx(gsh[p][512 + j] + bias_s[512 + j]);
      float go = sigm (gsh[p][768 + j] + bias_s[768 + j]);
      float c = gf * cT[p][j] + gi * gg;
      cT[p][j] = c;
      float h = go * tanhx(c);
      unsigned short hi = f2b(h);
      hS[p][j]     = hi;
      hS[p + 8][j] = f2b(h - b2f((unsigned int)hi));
    }
    __syncthreads();

    if (Wv < 4) {
      bf16x8 bh[8];
      #pragma unroll
      for (int kc = 0; kc < 8; ++kc)
        bh[kc] = *(const bf16x8*)&hS[lr][kc * 32 + (l >> 4) * 8];
      const unsigned short* tb = wb + WB_W2 + Wv * 8192 + l * 8;
      f32x4 aH = {0.f,0.f,0.f,0.f}, aL = {0.f,0.f,0.f,0.f};
      #pragma unroll
      for (int kc = 0; kc < 8; ++kc) {
        aH = mfma16(bh[kc], *(const bf16x8*)(tb + kc * 512), aH);
        aL = mfma16(bh[kc], *(const bf16x8*)(tb + 4096 + kc * 512), aL);
      }
      f32x4 acc = aH + aL;
      float s0 = acc[0] + __shfl_xor(acc[0], 32, 64);
      float s1 = acc[1] + __shfl_xor(acc[1], 32, 64);
      float s2 = acc[2] + __shfl_xor(acc[2], 32, 64);
      float s3 = acc[3] + __shfl_xor(acc[3], 32, 64);
      if (l < 32) {
        const int g = Wv * 16 + (l & 15), pb = (l >> 4) * 4;
        b2s[pb + 0][g] = s0; b2s[pb + 1][g] = s1;
        b2s[pb + 2][g] = s2; b2s[pb + 3][g] = s3;
      }
    }
    __syncthreads();

    if (t < 400) {
      int p = t / 50, j = t - p * 50;
      const float* bl = ws + O_BLEND1 + (((bbase + p) * 50 + j) * 64);
      float acc = 0.f;
      #pragma unroll
      for (int v4 = 0; v4 < 16; ++v4) {
        float4 bv = *(const float4*)(bl + v4 * 4);
        int w0 = v4 * 4;
        acc += vt_s[w0 + 0] * tanhx(bv.x + b2s[p][w0 + 0]);
        acc += vt_s[w0 + 1] * tanhx(bv.y + b2s[p][w0 + 1]);
        acc += vt_s[w0 + 2] * tanhx(bv.z + b2s[p][w0 + 2]);
        acc += vt_s[w0 + 3] * tanhx(bv.w + b2s[p][w0 + 3]);
      }
      outs[p][j] = selb[p][j] ? NEG_INF_V : acc;
    }
    __syncthreads();

    {
      int p = Wv, lane = l;
      float v = (lane < 50) ? outs[p][lane] : -3.4e38f;
      int idx = lane;
      #pragma unroll
      for (int msk = 1; msk < 64; msk <<= 1) {
        float ov = __shfl_xor(v, msk, 64);
        int   oi = __shfl_xor(idx, msk, 64);
        if (ov > v || (ov == v && oi < idx)) { v = ov; idx = oi; }
      }
      float e = (lane < 50) ? __expf(outs[p][lane] - v) : 0.f;
      float ssum = e;
      #pragma unroll
      for (int msk = 1; msk < 64; msk <<= 1) ssum += __shfl_xor(ssum, msk, 64);
      if (lane < 50) {
        float prob = fmaxf(e / ssum, 1e-9f);
        int o = (bbase + p) * 2500 + step * 50 + lane;
        if (b16) ((unsigned short*)outp)[o] = f2b(prob);
        else     ((float*)outp)[o] = prob;
      }
      if (lane == 0) selidx[p] = idx;
      if (lane == idx) selb[p][idx] = 1;
    }
    __syncthreads();

    for (int k = t; k < 1024; k += 512) {
      int p = k >> 7, i = k & 127;
      float xf = ldv(targets, b16,
                     ((long long)(bbase + p) * 50 + selidx[p]) * 128 + i);
      unsigned short hi = f2b(xf);
      xA[p][i]     = hi;
      xA[p + 8][i] = f2b(xf - b2f((unsigned int)hi));
    }
    __syncthreads();
  }
}

extern "C" void kernel_launch(void* const* d_in, const int* in_sizes, int n_in,
                              void* d_out, int out_size, void* d_ws, size_t ws_size,
                              hipStream_t stream) {
  (void)in_sizes; (void)n_in; (void)out_size;
  const void* targets = d_in[0];
  const void* h0      = d_in[1];
  const void* c0      = d_in[2];
  const void* W_enc   = d_in[3];
  const void* b_enc   = d_in[4];
  const void* W_ih    = d_in[5];
  const void* W_hh    = d_in[6];
  const void* b_ih    = d_in[7];
  const void* b_hh    = d_in[8];
  const void* W1      = d_in[9];
  const void* W2      = d_in[10];
  const void* vt      = d_in[11];
  float* ws = (float*)d_ws;

  int use_xw = (ws_size >= ((size_t)O_XW + (size_t)XW_FLOATS) * 4) ? 1 : 0;

  prepAll<<<1024, 256, 0, stream>>>(b_enc, b_ih, b_hh, W1, W_ih, W_hh, W2, ws);
  prep1<<<32, 256, 0, stream>>>(W_enc, W1, b_enc, ws);
  blendk<<<1024, 256, 0, stream>>>(targets, ws);
  if (use_xw) {
    xwK<<<256, 512, 0, stream>>>(targets, ws);
    mainX<<<256, 1024, 0, stream>>>(targets, h0, c0, vt, ws, d_out);
  } else {
    mainK6<<<128, 512, 0, stream>>>(targets, h0, c0, vt, ws, d_out);
  }
}

// Round 12
// 856.138 us; speedup vs baseline: 1.4634x; 1.1585x over previous
//
#include <hip/hip_runtime.h>

// ---------------- ws layout (float offsets) ----------------
#define O_WC     16
#define O_BC     (16 + 8192)
#define O_BIAS   (O_BC + 64)
#define O_BLEND1 16384
#define O_WB     3293184        // packed hi/lo weights (ushort region), 409600 floats
#define O_XW     4194304        // xw table [1024][50][1024] fp32 (use_xw only)
#define XW_FLOATS 52428800ULL
#define NEG_INF_V (-1.0e9f)

// packed weight region (ushort offsets). Gate tile nt (0..63) stride WB_TILE:
//   [0,4096) hhH kc*512+lane*8+e | [4096,8192) hhL
//   [8192,10240) ihH kc*512+lane*8+e | [10240,12288) ihL
// W2 tile ntw (0..3) at WB_W2 + ntw*8192: [0,4096) hi, [4096,8192) lo.
#define WB_TILE 12288
#define WB_W2   786432

using bf16x8 = __attribute__((ext_vector_type(8))) __bf16;
using f32x4  = __attribute__((ext_vector_type(4))) float;

__device__ __forceinline__ f32x4 mfma16(bf16x8 a, bf16x8 b, f32x4 c) {
  return __builtin_amdgcn_mfma_f32_16x16x32_bf16(a, b, c, 0, 0, 0);
}

__device__ __forceinline__ float b2f(unsigned int u) {
  union { unsigned int i; float f; } x; x.i = u << 16; return x.f;
}
__device__ __forceinline__ unsigned short f2b(float f) {
  union { float f; unsigned int i; } x; x.f = f;
  unsigned int r = x.i + 0x7fffu + ((x.i >> 16) & 1u);
  return (unsigned short)(r >> 16);
}
__device__ __forceinline__ float ldv(const void* p, int b16, long long i) {
  if (b16) return b2f(((const unsigned short*)p)[i]);
  return ((const float*)p)[i];
}
__device__ __forceinline__ float sigm(float x)  { return 1.0f / (1.0f + __expf(-x)); }
__device__ __forceinline__ float tanhx(float x) { return 1.0f - 2.0f / (1.0f + __expf(2.0f * x)); }

__device__ __forceinline__ float bfsel(const uint4& u, int e) {
  unsigned int w = (e < 2) ? u.x : (e < 4) ? u.y : (e < 6) ? u.z : u.w;
  union { unsigned int i; float f; } x;
  x.i = (e & 1) ? (w & 0xffff0000u) : (w << 16);
  return x.f;
}

// ---------------- prepAll: fused prep0 + wprep ----------------
__global__ __launch_bounds__(256) void prepAll(
    const void* b_enc, const void* b_ih, const void* b_hh, const void* W1,
    const void* W_ih, const void* W_hh, const void* W2, float* ws) {
  __shared__ int anybig;
  const int t = threadIdx.x;
  const int blk = blockIdx.x;
  if (t == 0) anybig = 0;
  __syncthreads();
  {
    unsigned short u = ((const unsigned short*)b_enc)[t];
    float f = b2f((unsigned int)u);
    if (!(fabsf(f) <= 1.0f)) atomicOr(&anybig, 1);
  }
  __syncthreads();
  const int b16 = anybig ? 0 : 1;

  if (blk == 0) {
    if (t == 0) ((int*)ws)[0] = b16;
    for (int k = t; k < 1024; k += 256)
      ws[O_BIAS + k] = ldv(b_ih, b16, k) + ldv(b_hh, b16, k);
    if (t < 64) {
      float acc = 0.f;
      for (int h = 0; h < 256; ++h)
        acc += ldv(W1, b16, t * 256 + h) * ldv(b_enc, b16, h);
      ws[O_BC + t] = acc;
    }
  }
  unsigned short* wb = (unsigned short*)(ws + O_WB);
  const int i = blk * 256 + t;   // 0..262143
  {  // W_hh [1024][256]
    int g = i >> 8, k = i & 255;
    int nt = g >> 4, r = g & 15;
    int kc = k >> 5, lane = ((k >> 3) & 3) * 16 + r, e = k & 7;
    float w = ldv(W_hh, b16, i);
    unsigned short hi = f2b(w);
    long long d = (long long)nt * WB_TILE + kc * 512 + lane * 8 + e;
    wb[d] = hi;
    wb[d + 4096] = f2b(w - b2f((unsigned int)hi));
  }
  if (i < 131072) {  // W_ih [1024][128]
    int g = i >> 7, k = i & 127;
    int nt = g >> 4, r = g & 15;
    int kc = k >> 5, lane = ((k >> 3) & 3) * 16 + r, e = k & 7;
    float w = ldv(W_ih, b16, i);
    unsigned short hi = f2b(w);
    long long d = (long long)nt * WB_TILE + 8192 + kc * 512 + lane * 8 + e;
    wb[d] = hi;
    wb[d + 2048] = f2b(w - b2f((unsigned int)hi));
  }
  if (i < 16384) {   // W2 [64][256]
    int g = i >> 8, k = i & 255;
    int ntw = g >> 4, r = g & 15;
    int kc = k >> 5, lane = ((k >> 3) & 3) * 16 + r, e = k & 7;
    float w = ldv(W2, b16, i);
    unsigned short hi = f2b(w);
    long long d = WB_W2 + ntw * 8192 + kc * 512 + lane * 8 + e;
    wb[d] = hi;
    wb[d + 4096] = f2b(w - b2f((unsigned int)hi));
  }
}

// ---------------- prep1: Wc = W1 @ W_enc ----------------
__global__ void prep1(const void* W_enc, const void* W1, const void* b_enc,
                      float* ws) {
  __shared__ int anybig;
  int t = threadIdx.x;
  if (t == 0) anybig = 0;
  __syncthreads();
  {
    unsigned short u = ((const unsigned short*)b_enc)[t];
    float f = b2f((unsigned int)u);
    if (!(fabsf(f) <= 1.0f)) atomicOr(&anybig, 1);
  }
  __syncthreads();
  int b16 = anybig ? 0 : 1;
  int o = blockIdx.x * 256 + t;
  int w = o >> 7, i = o & 127;
  float acc = 0.f;
  for (int h = 0; h < 256; ++h)
    acc += ldv(W1, b16, w * 256 + h) * ldv(W_enc, b16, h * 128 + i);
  ws[O_WC + o] = acc;
}

// ---------------- blendk: blend1 = targets @ Wc^T + bc ----------------
__global__ __launch_bounds__(256) void blendk(const void* targets, float* ws) {
  __shared__ float tg[6400];
  __shared__ float wc[8192];
  int b16 = ((const int*)ws)[0];
  int t = threadIdx.x, b = blockIdx.x;
  for (int k = t; k < 8192; k += 256) wc[k] = ws[O_WC + k];
  if (b16) {
    const unsigned short* tp = (const unsigned short*)targets + (long long)b * 6400;
    for (int k = t * 8; k < 6400; k += 2048) {
      uint4 u = *(const uint4*)(tp + k);
      #pragma unroll
      for (int e = 0; e < 8; ++e) tg[k + e] = bfsel(u, e);
    }
  } else {
    const float* tp = (const float*)targets + (long long)b * 6400;
    for (int k = t; k < 6400; k += 256) tg[k] = tp[k];
  }
  __syncthreads();
  int w = t & 63, j0 = t >> 6;
  float bcv = ws[O_BC + w];
  for (int j = j0; j < 50; j += 4) {
    float acc = 0.f;
    for (int i0 = 0; i0 < 128; i0 += 8) {
      const float4* q = (const float4*)(wc + w * 128 + i0);
      float4 a = q[0], bb = q[1];
      const float* x = &tg[j * 128 + i0];
      acc += a.x * x[0] + a.y * x[1] + a.z * x[2] + a.w * x[3]
           + bb.x * x[4] + bb.y * x[5] + bb.z * x[6] + bb.w * x[7];
    }
    ws[O_BLEND1 + (b * 50 + j) * 64 + w] = acc + bcv;
  }
}

// ---------------- xwK: xw[b][j][g] = targets[b,j,:].W_ih[g,:] (hi/lo MFMA) ----
__global__ __launch_bounds__(512)
__attribute__((amdgpu_waves_per_eu(2, 2)))
void xwK(const void* targets, float* ws) {
  __shared__ __align__(16) unsigned short tgS[4][32][264]; // hi 0-127, lo 128-255
  const int b16 = ((const int*)ws)[0];
  const int t = threadIdx.x;
  const int b0 = blockIdx.x * 4;
  const unsigned short* wb = (const unsigned short*)(ws + O_WB);
  float* xwp = ws + O_XW;
  const int l = t & 63, Wv = t >> 6, lr = l & 15, hc = l >> 4;

  #pragma unroll 1
  for (int half = 0; half < 2; ++half) {
    __syncthreads();
    for (int k = t; k < 4 * 32 * 128; k += 512) {
      int p = k >> 12, jr = (k >> 7) & 31, i = k & 127;
      int j = half * 32 + jr;
      float v = (j < 50) ? ldv(targets, b16, ((long long)(b0 + p) * 50 + j) * 128 + i)
                         : 0.f;
      unsigned short hi = f2b(v);
      tgS[p][jr][i]       = hi;
      tgS[p][jr][128 + i] = f2b(v - b2f((unsigned int)hi));
    }
    __syncthreads();
    const int njg = (half == 0) ? 4 : 3;
    #pragma unroll 1
    for (int ti = 0; ti < 8; ++ti) {
      const int nt = Wv * 8 + ti;
      const unsigned short* tb = wb + (long long)nt * WB_TILE + 8192 + l * 8;
      bf16x8 wih[8];
      #pragma unroll
      for (int kc = 0; kc < 4; ++kc) {
        wih[kc]     = *(const bf16x8*)(tb + kc * 512);
        wih[4 + kc] = *(const bf16x8*)(tb + 2048 + kc * 512);
      }
      #pragma unroll 1
      for (int p = 0; p < 4; ++p) {
        #pragma unroll 1
        for (int jh = 0; jh < njg; ++jh) {
          bf16x8 ax[4];
          const unsigned short* tp =
              &tgS[p][jh * 8 + (lr & 7)][((lr < 8) ? 0 : 128) + hc * 8];
          #pragma unroll
          for (int kc = 0; kc < 4; ++kc) ax[kc] = *(const bf16x8*)(tp + kc * 32);
          f32x4 cH = {0.f,0.f,0.f,0.f}, cL = {0.f,0.f,0.f,0.f};
          #pragma unroll
          for (int kc = 0; kc < 4; ++kc) {
            cH = mfma16(ax[kc], wih[kc], cH);
            cL = mfma16(ax[kc], wih[4 + kc], cL);
          }
          f32x4 acc = cH + cL;
          float s0 = acc[0] + __shfl_xor(acc[0], 32, 64);
          float s1 = acc[1] + __shfl_xor(acc[1], 32, 64);
          float s2 = acc[2] + __shfl_xor(acc[2], 32, 64);
          float s3 = acc[3] + __shfl_xor(acc[3], 32, 64);
          if (l < 32) {
            int jb = half * 32 + jh * 8 + hc * 4;
            long long ro = (long long)(b0 + p) * 50;
            if (jb + 0 < 50) xwp[(ro + jb + 0) * 1024 + nt * 16 + lr] = s0;
            if (jb + 1 < 50) xwp[(ro + jb + 1) * 1024 + nt * 16 + lr] = s1;
            if (jb + 2 < 50) xwp[(ro + jb + 2) * 1024 + nt * 16 + lr] = s2;
            if (jb + 3 < 50) xwp[(ro + jb + 3) * 1024 + nt * 16 + lr] = s3;
          }
        }
      }
    }
  }
}

// ---------------- mainX: producer/consumer wave split -------------------------
// Per step: A2 (all waves) | barrier | waves 4-15 stream NEXT step's gates GEMM
// (h_s @ W_hh -> gsh, 5-6 tiles each, depth-4 pipeline) CONCURRENT with waves
// 0-3: blend2 -> spin-sync(4 waves) -> fused C+argmax (1 wave/batch, blend1 in
// LDS) -> probs + xw prefetch | barrier. Prologue fills gsh for step 0.
__global__ __launch_bounds__(1024)
__attribute__((amdgpu_waves_per_eu(4, 4)))
void mainX(const void* targets, const void* h0, const void* c0, const void* vt,
           float* ws, void* outp) {
  __shared__ __align__(16) unsigned short hS[16][264];  // 0-3 hi, 4-7 lo, 8-15 zero
  __shared__ __align__(16) float xwS[4][1024];          // prefetched xw rows
  __shared__ float bl1S[4][50][66];                     // blend1, pad 66 (bank)
  __shared__ float cT[4][256];
  __shared__ float gsh[4][1024];
  __shared__ float bias_s[1024];
  __shared__ float b2s[4][64];
  __shared__ float vt_s[64];
  __shared__ int   selidx[4];
  __shared__ int   selb[4][64];
  __shared__ int   auxcnt;

  const int b16 = ((const int*)ws)[0];
  const int t = threadIdx.x;
  const int bbase = blockIdx.x * 4;
  const unsigned short* wb = (const unsigned short*)(ws + O_WB);
  const float* xw = ws + O_XW;

  bias_s[t] = ws[O_BIAS + t];
  if (t < 64) vt_s[t] = ldv(vt, b16, t);
  if (t < 256) selb[t >> 6][t & 63] = 0;
  if (t < 4) selidx[t] = -1;
  if (t == 0) auxcnt = 0;
  {
    unsigned short* z1 = &hS[0][0];
    for (int k = t; k < 16 * 264; k += 1024) z1[k] = 0;
  }
  for (int k = t; k < 12800; k += 1024) {    // blend1 -> LDS
    int p = k / 3200, r = k - p * 3200, j = r >> 6, w = r & 63;
    bl1S[p][j][w] = ws[O_BLEND1 + (((long long)(bbase + p) * 50 + j) << 6) + w];
  }
  __syncthreads();
  {
    int p = t >> 8, j = t & 255;
    float h = ldv(h0, b16, (long long)(bbase + p) * 256 + j);
    float c = ldv(c0, b16, (long long)(bbase + p) * 256 + j);
    unsigned short hi = f2b(h);
    hS[p][j]     = hi;
    hS[p + 4][j] = f2b(h - b2f((unsigned int)hi));
    cT[p][j]     = c;
  }
  __syncthreads();

  const int l  = t & 63, Wv = t >> 6;   // lane, wave (0..15)
  const int lr = l & 15, hc = l >> 4;

  // ---- prologue: gsh for step 0 (all 16 waves, 4 tiles each) ----
  {
    bf16x8 ah[8];
    #pragma unroll
    for (int kc = 0; kc < 8; ++kc)
      ah[kc] = *(const bf16x8*)&hS[lr][kc * 32 + hc * 8];
    #pragma unroll 1
    for (int nt = Wv; nt < 64; nt += 16) {
      const unsigned short* tb = wb + (long long)nt * WB_TILE + l * 8;
      bf16x8 wh[4], wl[4];
      #pragma unroll
      for (int q2 = 0; q2 < 4; ++q2) {
        wh[q2] = *(const bf16x8*)(tb + q2 * 512);
        wl[q2] = *(const bf16x8*)(tb + 4096 + q2 * 512);
      }
      f32x4 aH = {0.f,0.f,0.f,0.f}, aL = {0.f,0.f,0.f,0.f};
      #pragma unroll
      for (int kc = 0; kc < 8; ++kc) {
        const int cur = kc & 3;
        aH = mfma16(ah[kc], wh[cur], aH);
        aL = mfma16(ah[kc], wl[cur], aL);
        if (kc + 4 < 8) {
          wh[cur] = *(const bf16x8*)(tb + (kc + 4) * 512);
          wl[cur] = *(const bf16x8*)(tb + 4096 + (kc + 4) * 512);
        }
      }
      f32x4 acc = aH + aL;
      float s0 = acc[0] + __shfl_xor(acc[0], 16, 64);
      float s1 = acc[1] + __shfl_xor(acc[1], 16, 64);
      float s2 = acc[2] + __shfl_xor(acc[2], 16, 64);
      float s3 = acc[3] + __shfl_xor(acc[3], 16, 64);
      if (l < 16) {
        const int g = nt * 16 + l;
        gsh[0][g] = s0; gsh[1][g] = s1; gsh[2][g] = s2; gsh[3][g] = s3;
      }
    }
  }
  __syncthreads();

  #pragma unroll 1
  for (int step = 0; step < 50; ++step) {
    // ---- phase A2 (all waves): gates -> h_s; writes hS, cT ----
    {
      int j = t & 255, p = t >> 8;
      float gi = gsh[p][j], gf = gsh[p][256 + j];
      float gg = gsh[p][512 + j], go = gsh[p][768 + j];
      if (selidx[p] >= 0) {
        gi += xwS[p][j]; gf += xwS[p][256 + j];
        gg += xwS[p][512 + j]; go += xwS[p][768 + j];
      }
      gi = sigm (gi + bias_s[j]);
      gf = sigm (gf + bias_s[256 + j]);
      gg = tanhx(gg + bias_s[512 + j]);
      go = sigm (go + bias_s[768 + j]);
      float c = gf * cT[p][j] + gi * gg;
      cT[p][j] = c;
      float h = go * tanhx(c);
      unsigned short hi = f2b(h);
      hS[p][j]     = hi;
      hS[p + 4][j] = f2b(h - b2f((unsigned int)hi));
    }
    __syncthreads();

    if (Wv >= 4) {
      // ---- producer: next step's gates GEMM (waves 4-15, tiles nt=Wv-4+12k) ----
      if (step < 49) {
        bf16x8 ah[8];
        #pragma unroll
        for (int kc = 0; kc < 8; ++kc)
          ah[kc] = *(const bf16x8*)&hS[lr][kc * 32 + hc * 8];
        #pragma unroll 1
        for (int nt = Wv - 4; nt < 64; nt += 12) {
          const unsigned short* tb = wb + (long long)nt * WB_TILE + l * 8;
          bf16x8 wh[4], wl[4];
          #pragma unroll
          for (int q2 = 0; q2 < 4; ++q2) {
            wh[q2] = *(const bf16x8*)(tb + q2 * 512);
            wl[q2] = *(const bf16x8*)(tb + 4096 + q2 * 512);
          }
          f32x4 aH = {0.f,0.f,0.f,0.f}, aL = {0.f,0.f,0.f,0.f};
          #pragma unroll
          for (int kc = 0; kc < 8; ++kc) {
            const int cur = kc & 3;
            aH = mfma16(ah[kc], wh[cur], aH);
            aL = mfma16(ah[kc], wl[cur], aL);
            if (kc + 4 < 8) {
              wh[cur] = *(const bf16x8*)(tb + (kc + 4) * 512);
              wl[cur] = *(const bf16x8*)(tb + 4096 + (kc + 4) * 512);
            }
          }
          f32x4 acc = aH + aL;
          float s0 = acc[0] + __shfl_xor(acc[0], 16, 64);
          float s1 = acc[1] + __shfl_xor(acc[1], 16, 64);
          float s2 = acc[2] + __shfl_xor(acc[2], 16, 64);
          float s3 = acc[3] + __shfl_xor(acc[3], 16, 64);
          if (l < 16) {
            const int g = nt * 16 + l;
            gsh[0][g] = s0; gsh[1][g] = s1; gsh[2][g] = s2; gsh[3][g] = s3;
          }
        }
      }
    } else {
      // ---- consumer (waves 0-3): blend2 -> sync -> C+argmax -> probs/prefetch --
      {
        bf16x8 bh[8];
        #pragma unroll
        for (int kc = 0; kc < 8; ++kc)
          bh[kc] = *(const bf16x8*)&hS[lr][kc * 32 + hc * 8];
        const unsigned short* tb2 = wb + WB_W2 + Wv * 8192 + l * 8;
        f32x4 cH = {0.f,0.f,0.f,0.f}, cL = {0.f,0.f,0.f,0.f};
        #pragma unroll
        for (int kc = 0; kc < 8; ++kc) {
          cH = mfma16(bh[kc], *(const bf16x8*)(tb2 + kc * 512), cH);
          cL = mfma16(bh[kc], *(const bf16x8*)(tb2 + 4096 + kc * 512), cL);
        }
        f32x4 acc = cH + cL;
        float s0 = acc[0] + __shfl_xor(acc[0], 16, 64);
        float s1 = acc[1] + __shfl_xor(acc[1], 16, 64);
        float s2 = acc[2] + __shfl_xor(acc[2], 16, 64);
        float s3 = acc[3] + __shfl_xor(acc[3], 16, 64);
        if (l < 16) {
          const int g = Wv * 16 + l;
          b2s[0][g] = s0; b2s[1][g] = s1; b2s[2][g] = s2; b2s[3][g] = s3;
        }
      }
      // spin-sync among the 4 consumer waves (cumulative counter, no reset)
      __threadfence_block();
      if (l == 0)
        __hip_atomic_fetch_add(&auxcnt, 1, __ATOMIC_RELEASE,
                               __HIP_MEMORY_SCOPE_WORKGROUP);
      while (__hip_atomic_load(&auxcnt, __ATOMIC_ACQUIRE,
                               __HIP_MEMORY_SCOPE_WORKGROUP) < 4 * (step + 1))
        __builtin_amdgcn_s_sleep(2);

      // fused C + argmax: wave p handles batch p entirely
      {
        const int p = Wv, lane = l;
        float outv = -3.4e38f;
        if (lane < 50) {
          float acc = 0.f;
          #pragma unroll 8
          for (int w = 0; w < 64; ++w)
            acc += vt_s[w] * tanhx(bl1S[p][lane][w] + b2s[p][w]);
          outv = selb[p][lane] ? NEG_INF_V : acc;
        }
        float v = outv;
        int idx = lane;
        #pragma unroll
        for (int msk = 1; msk < 64; msk <<= 1) {
          float ov = __shfl_xor(v, msk, 64);
          int   oi = __shfl_xor(idx, msk, 64);
          if (ov > v || (ov == v && oi < idx)) { v = ov; idx = oi; }
        }
        // prefetch next step's xw row into LDS (idx known in-register)
        {
          const float* xr = xw + ((long long)(bbase + p) * 50 + idx) * 1024;
          #pragma unroll
          for (int kk = 0; kk < 4; ++kk)
            *(float4*)&xwS[p][lane * 4 + kk * 256] =
                *(const float4*)(xr + lane * 4 + kk * 256);
        }
        float e = (lane < 50) ? __expf(outv - v) : 0.f;
        float ssum = e;
        #pragma unroll
        for (int msk = 1; msk < 64; msk <<= 1) ssum += __shfl_xor(ssum, msk, 64);
        if (lane < 50) {
          float prob = fmaxf(e / ssum, 1e-9f);
          long long o = (long long)(bbase + p) * 2500 + step * 50 + lane;
          if (b16) ((unsigned short*)outp)[o] = f2b(prob);
          else     ((float*)outp)[o] = prob;
        }
        if (lane == 0) selidx[p] = idx;
        if (lane == idx) selb[p][idx] = 1;
      }
    }
    __syncthreads();
  }
}

// ---------------- mainK6: fallback (round-6-proven, no xw table) ----------------
__global__ __launch_bounds__(512)
__attribute__((amdgpu_waves_per_eu(2, 2)))
void mainK6(const void* targets, const void* h0, const void* c0, const void* vt,
            float* ws, void* outp) {
  __shared__ __align__(16) unsigned short hS[16][264];
  __shared__ __align__(16) unsigned short xA[16][136];
  __shared__ float cT[8][256];
  __shared__ float gsh[8][1024];
  __shared__ float bias_s[1024];
  __shared__ float b2s[8][64];
  __shared__ float outs[8][64];
  __shared__ float vt_s[64];
  __shared__ int   selidx[8];
  __shared__ int   selb[8][64];

  const int b16 = ((const int*)ws)[0];
  const int t = threadIdx.x;
  const int bbase = blockIdx.x * 8;
  const unsigned short* wb = (const unsigned short*)(ws + O_WB);

  for (int k = t; k < 1024; k += 512) bias_s[k] = ws[O_BIAS + k];
  if (t < 64) vt_s[t] = ldv(vt, b16, t);
  if (t < 512) selb[t >> 6][t & 63] = 0;
  if (t < 8) selidx[t] = -1;
  {
    unsigned short* z1 = &hS[0][0];
    unsigned short* z2 = &xA[0][0];
    for (int k = t; k < 16 * 264; k += 512) z1[k] = 0;
    for (int k = t; k < 16 * 136; k += 512) z2[k] = 0;
  }
  __syncthreads();
  for (int k = t; k < 2048; k += 512) {
    int p = k >> 8, j = k & 255;
    float h = ldv(h0, b16, (long long)(bbase + p) * 256 + j);
    float c = ldv(c0, b16, (long long)(bbase + p) * 256 + j);
    unsigned short hi = f2b(h);
    hS[p][j]     = hi;
    hS[p + 8][j] = f2b(h - b2f((unsigned int)hi));
    cT[p][j]     = c;
  }
  __syncthreads();

  const int l  = t & 63, Wv = t >> 6;
  const int lr = l & 15;

  #pragma unroll 1
  for (int step = 0; step < 50; ++step) {
    {
      bf16x8 ah[8], ax[4];
      #pragma unroll
      for (int kc = 0; kc < 8; ++kc)
        ah[kc] = *(const bf16x8*)&hS[lr][kc * 32 + (l >> 4) * 8];
      #pragma unroll
      for (int kc = 0; kc < 4; ++kc)
        ax[kc] = *(const bf16x8*)&xA[lr][kc * 32 + (l >> 4) * 8];
      #pragma unroll 1
      for (int ti = 0; ti < 8; ++ti) {
        const int nt = Wv * 8 + ti;
        const unsigned short* tb = wb + (long long)nt * WB_TILE + l * 8;
        bf16x8 wH[12], wL[12];
        #pragma unroll
        for (int kc = 0; kc < 8; ++kc) {
          wH[kc] = *(const bf16x8*)(tb + kc * 512);
          wL[kc] = *(const bf16x8*)(tb + 4096 + kc * 512);
        }
        #pragma unroll
        for (int kc = 0; kc < 4; ++kc) {
          wH[8 + kc] = *(const bf16x8*)(tb + 8192 + kc * 512);
          wL[8 + kc] = *(const bf16x8*)(tb + 10240 + kc * 512);
        }
        f32x4 aH = {0.f,0.f,0.f,0.f}, aL = {0.f,0.f,0.f,0.f};
        #pragma unroll
        for (int kc = 0; kc < 8; ++kc) {
          aH = mfma16(ah[kc], wH[kc], aH);
          aL = mfma16(ah[kc], wL[kc], aL);
        }
        #pragma unroll
        for (int kc = 0; kc < 4; ++kc) {
          aH = mfma16(ax[kc], wH[8 + kc], aH);
          aL = mfma16(ax[kc], wL[8 + kc], aL);
        }
        f32x4 acc = aH + aL;
        float s0 = acc[0] + __shfl_xor(acc[0], 32, 64);
        float s1 = acc[1] + __shfl_xor(acc[1], 32, 64);
        float s2 = acc[2] + __shfl_xor(acc[2], 32, 64);
        float s3 = acc[3] + __shfl_xor(acc[3], 32, 64);
        if (l < 32) {
          const int g = nt * 16 + (l & 15), pb = (l >> 4) * 4;
          gsh[pb + 0][g] = s0; gsh[pb + 1][g] = s1;
          gsh[pb + 2][g] = s2; gsh[pb + 3][g] = s3;
        }
      }
    }
    __syncthreads();

    for (int k = t; k < 2048; k += 512) {
      int j = k & 255, p = k >> 8;
      float gi = sigm (gsh[p][j]       + bias_s[j]);
      float gf = sigm (gsh[p][256 + j] + bias_s[256 + j]);
      float gg = tanhx(gsh[p][512 + j] + bias_s[512 + j]);
      float go = sigm (gsh[p][768 + j] + bias_s[768 + j]);
      float c = gf * cT[p][j] + gi * gg;
      cT[p][j] = c;
      float h = go * tanhx(c);
      unsigned short hi = f2b(h);
      hS[p][j]     = hi;
      hS[p + 8][j] = f2b(h - b2f((unsigned int)hi));
    }
    __syncthreads();

    if (Wv < 4) {
      bf16x8 bh[8];
      #pragma unroll
      for (int kc = 0; kc < 8; ++kc)
        bh[kc] = *(const bf16x8*)&hS[lr][kc * 32 + (l >> 4) * 8];
      const unsigned short* tb = wb + WB_W2 + Wv * 8192 + l * 8;
      f32x4 aH = {0.f,0.f,0.f,0.f}, aL = {0.f,0.f,0.f,0.f};
      #pragma unroll
      for (int kc = 0; kc < 8; ++kc) {
        aH = mfma16(bh[kc], *(const bf16x8*)(tb + kc * 512), aH);
        aL = mfma16(bh[kc], *(const bf16x8*)(tb + 4096 + kc * 512), aL);
      }
      f32x4 acc = aH + aL;
      float s0 = acc[0] + __shfl_xor(acc[0], 32, 64);
      float s1 = acc[1] + __shfl_xor(acc[1], 32, 64);
      float s2 = acc[2] + __shfl_xor(acc[2], 32, 64);
      float s3 = acc[3] + __shfl_xor(acc[3], 32, 64);
      if (l < 32) {
        const int g = Wv * 16 + (l & 15), pb = (l >> 4) * 4;
        b2s[pb + 0][g] = s0; b2s[pb + 1][g] = s1;
        b2s[pb + 2][g] = s2; b2s[pb + 3][g] = s3;
      }
    }
    __syncthreads();

    if (t < 400) {
      int p = t / 50, j = t - p * 50;
      const float* bl = ws + O_BLEND1 + (((bbase + p) * 50 + j) * 64);
      float acc = 0.f;
      #pragma unroll
      for (int v4 = 0; v4 < 16; ++v4) {
        float4 bv = *(const float4*)(bl + v4 * 4);
        int w0 = v4 * 4;
        acc += vt_s[w0 + 0] * tanhx(bv.x + b2s[p][w0 + 0]);
        acc += vt_s[w0 + 1] * tanhx(bv.y + b2s[p][w0 + 1]);
        acc += vt_s[w0 + 2] * tanhx(bv.z + b2s[p][w0 + 2]);
        acc += vt_s[w0 + 3] * tanhx(bv.w + b2s[p][w0 + 3]);
      }
      outs[p][j] = selb[p][j] ? NEG_INF_V : acc;
    }
    __syncthreads();

    {
      int p = Wv, lane = l;
      float v = (lane < 50) ? outs[p][lane] : -3.4e38f;
      int idx = lane;
      #pragma unroll
      for (int msk = 1; msk < 64; msk <<= 1) {
        float ov = __shfl_xor(v, msk, 64);
        int   oi = __shfl_xor(idx, msk, 64);
        if (ov > v || (ov == v && oi < idx)) { v = ov; idx = oi; }
      }
      float e = (lane < 50) ? __expf(outs[p][lane] - v) : 0.f;
      float ssum = e;
      #pragma unroll
      for (int msk = 1; msk < 64; msk <<= 1) ssum += __shfl_xor(ssum, msk, 64);
      if (lane < 50) {
        float prob = fmaxf(e / ssum, 1e-9f);
        int o = (bbase + p) * 2500 + step * 50 + lane;
        if (b16) ((unsigned short*)outp)[o] = f2b(prob);
        else     ((float*)outp)[o] = prob;
      }
      if (lane == 0) selidx[p] = idx;
      if (lane == idx) selb[p][idx] = 1;
    }
    __syncthreads();

    for (int k = t; k < 1024; k += 512) {
      int p = k >> 7, i = k & 127;
      float xf = ldv(targets, b16,
                     ((long long)(bbase + p) * 50 + selidx[p]) * 128 + i);
      unsigned short hi = f2b(xf);
      xA[p][i]     = hi;
      xA[p + 8][i] = f2b(xf - b2f((unsigned int)hi));
    }
    __syncthreads();
  }
}

extern "C" void kernel_launch(void* const* d_in, const int* in_sizes, int n_in,
                              void* d_out, int out_size, void* d_ws, size_t ws_size,
                              hipStream_t stream) {
  (void)in_sizes; (void)n_in; (void)out_size;
  const void* targets = d_in[0];
  const void* h0      = d_in[1];
  const void* c0      = d_in[2];
  const void* W_enc   = d_in[3];
  const void* b_enc   = d_in[4];
  const void* W_ih    = d_in[5];
  const void* W_hh    = d_in[6];
  const void* b_ih    = d_in[7];
  const void* b_hh    = d_in[8];
  const void* W1      = d_in[9];
  const void* W2      = d_in[10];
  const void* vt      = d_in[11];
  float* ws = (float*)d_ws;

  int use_xw = (ws_size >= ((size_t)O_XW + (size_t)XW_FLOATS) * 4) ? 1 : 0;

  prepAll<<<1024, 256, 0, stream>>>(b_enc, b_ih, b_hh, W1, W_ih, W_hh, W2, ws);
  prep1<<<32, 256, 0, stream>>>(W_enc, W1, b_enc, ws);
  blendk<<<1024, 256, 0, stream>>>(targets, ws);
  if (use_xw) {
    xwK<<<256, 512, 0, stream>>>(targets, ws);
    mainX<<<256, 1024, 0, stream>>>(targets, h0, c0, vt, ws, d_out);
  } else {
    mainK6<<<128, 512, 0, stream>>>(targets, h0, c0, vt, ws, d_out);
  }
}

// Round 14
// 833.274 us; speedup vs baseline: 1.5035x; 1.0274x over previous
//
#include <hip/hip_runtime.h>

// ---------------- ws layout (float offsets) ----------------
#define O_WC     16
#define O_BC     (16 + 8192)
#define O_BIAS   (O_BC + 64)
#define O_BLEND1 16384
#define O_WB     3293184        // packed hi/lo weights (ushort region), 409600 floats
#define O_XW     4194304        // xw table [1024][50][1024] fp32 (use_xw only)
#define XW_FLOATS 52428800ULL
#define NEG_INF_V (-1.0e9f)

// packed weight region (ushort offsets). Gate tile nt (0..63) stride WB_TILE:
//   [0,4096) hhH kc*512+lane*8+e | [4096,8192) hhL
//   [8192,10240) ihH kc*512+lane*8+e | [10240,12288) ihL
// W2 tile ntw (0..3) at WB_W2 + ntw*8192: [0,4096) hi, [4096,8192) lo.
#define WB_TILE 12288
#define WB_W2   786432

using bf16x8 = __attribute__((ext_vector_type(8))) __bf16;
using f32x4  = __attribute__((ext_vector_type(4))) float;

__device__ __forceinline__ f32x4 mfma16(bf16x8 a, bf16x8 b, f32x4 c) {
  return __builtin_amdgcn_mfma_f32_16x16x32_bf16(a, b, c, 0, 0, 0);
}

__device__ __forceinline__ float b2f(unsigned int u) {
  union { unsigned int i; float f; } x; x.i = u << 16; return x.f;
}
__device__ __forceinline__ unsigned short f2b(float f) {
  union { float f; unsigned int i; } x; x.f = f;
  unsigned int r = x.i + 0x7fffu + ((x.i >> 16) & 1u);
  return (unsigned short)(r >> 16);
}
__device__ __forceinline__ float ldv(const void* p, int b16, long long i) {
  if (b16) return b2f(((const unsigned short*)p)[i]);
  return ((const float*)p)[i];
}
__device__ __forceinline__ float sigm(float x)  { return 1.0f / (1.0f + __expf(-x)); }
__device__ __forceinline__ float tanhx(float x) { return 1.0f - 2.0f / (1.0f + __expf(2.0f * x)); }

__device__ __forceinline__ float bfsel(const uint4& u, int e) {
  unsigned int w = (e < 2) ? u.x : (e < 4) ? u.y : (e < 6) ? u.z : u.w;
  union { unsigned int i; float f; } x;
  x.i = (e & 1) ? (w & 0xffff0000u) : (w << 16);
  return x.f;
}

// ---------------- prepAll: fused prep0 + wprep + prep1 (blocks >= 1024) -------
__global__ __launch_bounds__(256) void prepAll(
    const void* b_enc, const void* b_ih, const void* b_hh, const void* W1,
    const void* W_ih, const void* W_hh, const void* W2, const void* W_enc,
    float* ws) {
  __shared__ int anybig;
  const int t = threadIdx.x;
  const int blk = blockIdx.x;
  if (t == 0) anybig = 0;
  __syncthreads();
  {
    unsigned short u = ((const unsigned short*)b_enc)[t];
    float f = b2f((unsigned int)u);
    if (!(fabsf(f) <= 1.0f)) atomicOr(&anybig, 1);
  }
  __syncthreads();
  const int b16 = anybig ? 0 : 1;

  if (blk >= 1024) {   // prep1 role: Wc = W1 @ W_enc
    int o = (blk - 1024) * 256 + t;
    int w = o >> 7, ii = o & 127;
    float acc = 0.f;
    for (int h = 0; h < 256; ++h)
      acc += ldv(W1, b16, w * 256 + h) * ldv(W_enc, b16, h * 128 + ii);
    ws[O_WC + o] = acc;
    return;
  }

  if (blk == 0) {
    if (t == 0) ((int*)ws)[0] = b16;
    for (int k = t; k < 1024; k += 256)
      ws[O_BIAS + k] = ldv(b_ih, b16, k) + ldv(b_hh, b16, k);
    if (t < 64) {
      float acc = 0.f;
      for (int h = 0; h < 256; ++h)
        acc += ldv(W1, b16, t * 256 + h) * ldv(b_enc, b16, h);
      ws[O_BC + t] = acc;
    }
  }
  unsigned short* wb = (unsigned short*)(ws + O_WB);
  const int i = blk * 256 + t;   // 0..262143
  {  // W_hh [1024][256]
    int g = i >> 8, k = i & 255;
    int nt = g >> 4, r = g & 15;
    int kc = k >> 5, lane = ((k >> 3) & 3) * 16 + r, e = k & 7;
    float w = ldv(W_hh, b16, i);
    unsigned short hi = f2b(w);
    long long d = (long long)nt * WB_TILE + kc * 512 + lane * 8 + e;
    wb[d] = hi;
    wb[d + 4096] = f2b(w - b2f((unsigned int)hi));
  }
  if (i < 131072) {  // W_ih [1024][128]
    int g = i >> 7, k = i & 127;
    int nt = g >> 4, r = g & 15;
    int kc = k >> 5, lane = ((k >> 3) & 3) * 16 + r, e = k & 7;
    float w = ldv(W_ih, b16, i);
    unsigned short hi = f2b(w);
    long long d = (long long)nt * WB_TILE + 8192 + kc * 512 + lane * 8 + e;
    wb[d] = hi;
    wb[d + 2048] = f2b(w - b2f((unsigned int)hi));
  }
  if (i < 16384) {   // W2 [64][256]
    int g = i >> 8, k = i & 255;
    int ntw = g >> 4, r = g & 15;
    int kc = k >> 5, lane = ((k >> 3) & 3) * 16 + r, e = k & 7;
    float w = ldv(W2, b16, i);
    unsigned short hi = f2b(w);
    long long d = WB_W2 + ntw * 8192 + kc * 512 + lane * 8 + e;
    wb[d] = hi;
    wb[d + 4096] = f2b(w - b2f((unsigned int)hi));
  }
}

// ---------------- blendk: blend1 = targets @ Wc^T + bc ----------------
__global__ __launch_bounds__(256) void blendk(const void* targets, float* ws) {
  __shared__ float tg[6400];
  __shared__ float wc[8192];
  int b16 = ((const int*)ws)[0];
  int t = threadIdx.x, b = blockIdx.x;
  for (int k = t; k < 8192; k += 256) wc[k] = ws[O_WC + k];
  if (b16) {
    const unsigned short* tp = (const unsigned short*)targets + (long long)b * 6400;
    for (int k = t * 8; k < 6400; k += 2048) {
      uint4 u = *(const uint4*)(tp + k);
      #pragma unroll
      for (int e = 0; e < 8; ++e) tg[k + e] = bfsel(u, e);
    }
  } else {
    const float* tp = (const float*)targets + (long long)b * 6400;
    for (int k = t; k < 6400; k += 256) tg[k] = tp[k];
  }
  __syncthreads();
  int w = t & 63, j0 = t >> 6;
  float bcv = ws[O_BC + w];
  for (int j = j0; j < 50; j += 4) {
    float acc = 0.f;
    for (int i0 = 0; i0 < 128; i0 += 8) {
      const float4* q = (const float4*)(wc + w * 128 + i0);
      float4 a = q[0], bb = q[1];
      const float* x = &tg[j * 128 + i0];
      acc += a.x * x[0] + a.y * x[1] + a.z * x[2] + a.w * x[3]
           + bb.x * x[4] + bb.y * x[5] + bb.z * x[6] + bb.w * x[7];
    }
    ws[O_BLEND1 + (b * 50 + j) * 64 + w] = acc + bcv;
  }
}

// ---------------- xwK: xw[b][j][g] = targets[b,j,:].W_ih[g,:] (hi/lo MFMA) ----
__global__ __launch_bounds__(512)
__attribute__((amdgpu_waves_per_eu(2, 2)))
void xwK(const void* targets, float* ws) {
  __shared__ __align__(16) unsigned short tgS[4][32][264]; // hi 0-127, lo 128-255
  const int b16 = ((const int*)ws)[0];
  const int t = threadIdx.x;
  const int b0 = blockIdx.x * 4;
  const unsigned short* wb = (const unsigned short*)(ws + O_WB);
  float* xwp = ws + O_XW;
  const int l = t & 63, Wv = t >> 6, lr = l & 15, hc = l >> 4;

  #pragma unroll 1
  for (int half = 0; half < 2; ++half) {
    __syncthreads();
    for (int k = t; k < 4 * 32 * 128; k += 512) {
      int p = k >> 12, jr = (k >> 7) & 31, i = k & 127;
      int j = half * 32 + jr;
      float v = (j < 50) ? ldv(targets, b16, ((long long)(b0 + p) * 50 + j) * 128 + i)
                         : 0.f;
      unsigned short hi = f2b(v);
      tgS[p][jr][i]       = hi;
      tgS[p][jr][128 + i] = f2b(v - b2f((unsigned int)hi));
    }
    __syncthreads();
    const int njg = (half == 0) ? 4 : 3;
    #pragma unroll 1
    for (int ti = 0; ti < 8; ++ti) {
      const int nt = Wv * 8 + ti;
      const unsigned short* tb = wb + (long long)nt * WB_TILE + 8192 + l * 8;
      bf16x8 wih[8];
      #pragma unroll
      for (int kc = 0; kc < 4; ++kc) {
        wih[kc]     = *(const bf16x8*)(tb + kc * 512);
        wih[4 + kc] = *(const bf16x8*)(tb + 2048 + kc * 512);
      }
      #pragma unroll 1
      for (int p = 0; p < 4; ++p) {
        #pragma unroll 1
        for (int jh = 0; jh < njg; ++jh) {
          bf16x8 ax[4];
          const unsigned short* tp =
              &tgS[p][jh * 8 + (lr & 7)][((lr < 8) ? 0 : 128) + hc * 8];
          #pragma unroll
          for (int kc = 0; kc < 4; ++kc) ax[kc] = *(const bf16x8*)(tp + kc * 32);
          f32x4 cH = {0.f,0.f,0.f,0.f}, cL = {0.f,0.f,0.f,0.f};
          #pragma unroll
          for (int kc = 0; kc < 4; ++kc) {
            cH = mfma16(ax[kc], wih[kc], cH);
            cL = mfma16(ax[kc], wih[4 + kc], cL);
          }
          f32x4 acc = cH + cL;
          float s0 = acc[0] + __shfl_xor(acc[0], 32, 64);
          float s1 = acc[1] + __shfl_xor(acc[1], 32, 64);
          float s2 = acc[2] + __shfl_xor(acc[2], 32, 64);
          float s3 = acc[3] + __shfl_xor(acc[3], 32, 64);
          if (l < 32) {
            int jb = half * 32 + jh * 8 + hc * 4;
            long long ro = (long long)(b0 + p) * 50;
            if (jb + 0 < 50) xwp[(ro + jb + 0) * 1024 + nt * 16 + lr] = s0;
            if (jb + 1 < 50) xwp[(ro + jb + 1) * 1024 + nt * 16 + lr] = s1;
            if (jb + 2 < 50) xwp[(ro + jb + 2) * 1024 + nt * 16 + lr] = s2;
            if (jb + 3 < 50) xwp[(ro + jb + 3) * 1024 + nt * 16 + lr] = s3;
          }
        }
      }
    }
  }
}

// ---------------- mainX: producer/consumer wave split, balanced tiles ---------
// Per step: A2 (all waves) | barrier | producers (waves 4-15): 5 contiguous
// tiles each (nt = (Wv-4)*5 + k, tiles 0-59) of NEXT step's gates GEMM,
// CONCURRENT with consumers (waves 0-3): blend2 -> spin-sync -> fused C+argmax
// -> probs + xw prefetch -> 1 tile (60+Wv) | barrier.
__global__ __launch_bounds__(1024)
__attribute__((amdgpu_waves_per_eu(4, 4)))
void mainX(const void* targets, const void* h0, const void* c0, const void* vt,
           float* ws, void* outp) {
  __shared__ __align__(16) unsigned short hS[16][264];  // 0-3 hi, 4-7 lo, 8-15 zero
  __shared__ __align__(16) float xwS[4][1024];          // prefetched xw rows
  __shared__ float bl1S[4][50][66];                     // blend1, pad 66 (bank)
  __shared__ float cT[4][256];
  __shared__ float gsh[4][1024];
  __shared__ float bias_s[1024];
  __shared__ float b2s[4][64];
  __shared__ float vt_s[64];
  __shared__ int   selidx[4];
  __shared__ int   selb[4][64];
  __shared__ int   auxcnt;

  const int b16 = ((const int*)ws)[0];
  const int t = threadIdx.x;
  const int bbase = blockIdx.x * 4;
  const unsigned short* wb = (const unsigned short*)(ws + O_WB);
  const float* xw = ws + O_XW;

  bias_s[t] = ws[O_BIAS + t];
  if (t < 64) vt_s[t] = ldv(vt, b16, t);
  if (t < 256) selb[t >> 6][t & 63] = 0;
  if (t < 4) selidx[t] = -1;
  if (t == 0) auxcnt = 0;
  {
    unsigned short* z1 = &hS[0][0];
    for (int k = t; k < 16 * 264; k += 1024) z1[k] = 0;
  }
  for (int k = t; k < 12800; k += 1024) {    // blend1 -> LDS
    int p = k / 3200, r = k - p * 3200, j = r >> 6, w = r & 63;
    bl1S[p][j][w] = ws[O_BLEND1 + (((long long)(bbase + p) * 50 + j) << 6) + w];
  }
  __syncthreads();
  {
    int p = t >> 8, j = t & 255;
    float h = ldv(h0, b16, (long long)(bbase + p) * 256 + j);
    float c = ldv(c0, b16, (long long)(bbase + p) * 256 + j);
    unsigned short hi = f2b(h);
    hS[p][j]     = hi;
    hS[p + 4][j] = f2b(h - b2f((unsigned int)hi));
    cT[p][j]     = c;
  }
  __syncthreads();

  const int l  = t & 63, Wv = t >> 6;   // lane, wave (0..15)
  const int lr = l & 15, hc = l >> 4;

  // ---- prologue: gsh for step 0 (all 16 waves, 4 tiles each) ----
  {
    bf16x8 ah[8];
    #pragma unroll
    for (int kc = 0; kc < 8; ++kc)
      ah[kc] = *(const bf16x8*)&hS[lr][kc * 32 + hc * 8];
    #pragma unroll 1
    for (int nt = Wv; nt < 64; nt += 16) {
      const unsigned short* tb = wb + (long long)nt * WB_TILE + l * 8;
      bf16x8 wh[4], wl[4];
      #pragma unroll
      for (int q2 = 0; q2 < 4; ++q2) {
        wh[q2] = *(const bf16x8*)(tb + q2 * 512);
        wl[q2] = *(const bf16x8*)(tb + 4096 + q2 * 512);
      }
      f32x4 aH = {0.f,0.f,0.f,0.f}, aL = {0.f,0.f,0.f,0.f};
      #pragma unroll
      for (int kc = 0; kc < 8; ++kc) {
        const int cur = kc & 3;
        aH = mfma16(ah[kc], wh[cur], aH);
        aL = mfma16(ah[kc], wl[cur], aL);
        if (kc + 4 < 8) {
          wh[cur] = *(const bf16x8*)(tb + (kc + 4) * 512);
          wl[cur] = *(const bf16x8*)(tb + 4096 + (kc + 4) * 512);
        }
      }
      f32x4 acc = aH + aL;
      float s0 = acc[0] + __shfl_xor(acc[0], 16, 64);
      float s1 = acc[1] + __shfl_xor(acc[1], 16, 64);
      float s2 = acc[2] + __shfl_xor(acc[2], 16, 64);
      float s3 = acc[3] + __shfl_xor(acc[3], 16, 64);
      if (l < 16) {
        const int g = nt * 16 + l;
        gsh[0][g] = s0; gsh[1][g] = s1; gsh[2][g] = s2; gsh[3][g] = s3;
      }
    }
  }
  __syncthreads();

  #pragma unroll 1
  for (int step = 0; step < 50; ++step) {
    // ---- phase A2 (all waves): gates -> h_s; writes hS, cT ----
    {
      int j = t & 255, p = t >> 8;
      float gi = gsh[p][j], gf = gsh[p][256 + j];
      float gg = gsh[p][512 + j], go = gsh[p][768 + j];
      if (selidx[p] >= 0) {
        gi += xwS[p][j]; gf += xwS[p][256 + j];
        gg += xwS[p][512 + j]; go += xwS[p][768 + j];
      }
      gi = sigm (gi + bias_s[j]);
      gf = sigm (gf + bias_s[256 + j]);
      gg = tanhx(gg + bias_s[512 + j]);
      go = sigm (go + bias_s[768 + j]);
      float c = gf * cT[p][j] + gi * gg;
      cT[p][j] = c;
      float h = go * tanhx(c);
      unsigned short hi = f2b(h);
      hS[p][j]     = hi;
      hS[p + 4][j] = f2b(h - b2f((unsigned int)hi));
    }
    __syncthreads();

    if (Wv >= 4) {
      // ---- producers: 5 contiguous tiles each (tiles 0-59) ----
      if (step < 49) {
        bf16x8 ah[8];
        #pragma unroll
        for (int kc = 0; kc < 8; ++kc)
          ah[kc] = *(const bf16x8*)&hS[lr][kc * 32 + hc * 8];
        const int nt0 = (Wv - 4) * 5;
        #pragma unroll 1
        for (int k5 = 0; k5 < 5; ++k5) {
          const int nt = nt0 + k5;
          const unsigned short* tb = wb + (long long)nt * WB_TILE + l * 8;
          bf16x8 wh[4], wl[4];
          #pragma unroll
          for (int q2 = 0; q2 < 4; ++q2) {
            wh[q2] = *(const bf16x8*)(tb + q2 * 512);
            wl[q2] = *(const bf16x8*)(tb + 4096 + q2 * 512);
          }
          f32x4 aH = {0.f,0.f,0.f,0.f}, aL = {0.f,0.f,0.f,0.f};
          #pragma unroll
          for (int kc = 0; kc < 8; ++kc) {
            const int cur = kc & 3;
            aH = mfma16(ah[kc], wh[cur], aH);
            aL = mfma16(ah[kc], wl[cur], aL);
            if (kc + 4 < 8) {
              wh[cur] = *(const bf16x8*)(tb + (kc + 4) * 512);
              wl[cur] = *(const bf16x8*)(tb + 4096 + (kc + 4) * 512);
            }
          }
          f32x4 acc = aH + aL;
          float s0 = acc[0] + __shfl_xor(acc[0], 16, 64);
          float s1 = acc[1] + __shfl_xor(acc[1], 16, 64);
          float s2 = acc[2] + __shfl_xor(acc[2], 16, 64);
          float s3 = acc[3] + __shfl_xor(acc[3], 16, 64);
          if (l < 16) {
            const int g = nt * 16 + l;
            gsh[0][g] = s0; gsh[1][g] = s1; gsh[2][g] = s2; gsh[3][g] = s3;
          }
        }
      }
    } else {
      // ---- consumers (waves 0-3): blend2 -> sync -> C+argmax -> probs -> tile --
      {
        bf16x8 bh[8];
        #pragma unroll
        for (int kc = 0; kc < 8; ++kc)
          bh[kc] = *(const bf16x8*)&hS[lr][kc * 32 + hc * 8];
        const unsigned short* tb2 = wb + WB_W2 + Wv * 8192 + l * 8;
        f32x4 cH = {0.f,0.f,0.f,0.f}, cL = {0.f,0.f,0.f,0.f};
        #pragma unroll
        for (int kc = 0; kc < 8; ++kc) {
          cH = mfma16(bh[kc], *(const bf16x8*)(tb2 + kc * 512), cH);
          cL = mfma16(bh[kc], *(const bf16x8*)(tb2 + 4096 + kc * 512), cL);
        }
        f32x4 acc = cH + cL;
        float s0 = acc[0] + __shfl_xor(acc[0], 16, 64);
        float s1 = acc[1] + __shfl_xor(acc[1], 16, 64);
        float s2 = acc[2] + __shfl_xor(acc[2], 16, 64);
        float s3 = acc[3] + __shfl_xor(acc[3], 16, 64);
        if (l < 16) {
          const int g = Wv * 16 + l;
          b2s[0][g] = s0; b2s[1][g] = s1; b2s[2][g] = s2; b2s[3][g] = s3;
        }
      }
      // spin-sync among the 4 consumer waves (cumulative counter, no reset)
      __threadfence_block();
      if (l == 0)
        __hip_atomic_fetch_add(&auxcnt, 1, __ATOMIC_RELEASE,
                               __HIP_MEMORY_SCOPE_WORKGROUP);
      while (__hip_atomic_load(&auxcnt, __ATOMIC_ACQUIRE,
                               __HIP_MEMORY_SCOPE_WORKGROUP) < 4 * (step + 1))
        __builtin_amdgcn_s_sleep(2);

      // fused C + argmax: wave p handles batch p entirely
      {
        const int p = Wv, lane = l;
        float outv = -3.4e38f;
        if (lane < 50) {
          float acc = 0.f;
          #pragma unroll 8
          for (int w = 0; w < 64; ++w)
            acc += vt_s[w] * tanhx(bl1S[p][lane][w] + b2s[p][w]);
          outv = selb[p][lane] ? NEG_INF_V : acc;
        }
        float v = outv;
        int idx = lane;
        #pragma unroll
        for (int msk = 1; msk < 64; msk <<= 1) {
          float ov = __shfl_xor(v, msk, 64);
          int   oi = __shfl_xor(idx, msk, 64);
          if (ov > v || (ov == v && oi < idx)) { v = ov; idx = oi; }
        }
        // prefetch next step's xw row into LDS (idx known in-register)
        {
          const float* xr = xw + ((long long)(bbase + p) * 50 + idx) * 1024;
          #pragma unroll
          for (int kk = 0; kk < 4; ++kk)
            *(float4*)&xwS[p][lane * 4 + kk * 256] =
                *(const float4*)(xr + lane * 4 + kk * 256);
        }
        float e = (lane < 50) ? __expf(outv - v) : 0.f;
        float ssum = e;
        #pragma unroll
        for (int msk = 1; msk < 64; msk <<= 1) ssum += __shfl_xor(ssum, msk, 64);
        if (lane < 50) {
          float prob = fmaxf(e / ssum, 1e-9f);
          long long o = (long long)(bbase + p) * 2500 + step * 50 + lane;
          if (b16) ((unsigned short*)outp)[o] = f2b(prob);
          else     ((float*)outp)[o] = prob;
        }
        if (lane == 0) selidx[p] = idx;
        if (lane == idx) selb[p][idx] = 1;
      }
      // consumer's extra GEMM tile (60+Wv) for next step
      if (step < 49) {
        bf16x8 ah[8];
        #pragma unroll
        for (int kc = 0; kc < 8; ++kc)
          ah[kc] = *(const bf16x8*)&hS[lr][kc * 32 + hc * 8];
        const int nt = 60 + Wv;
        const unsigned short* tb = wb + (long long)nt * WB_TILE + l * 8;
        bf16x8 wh[4], wl[4];
        #pragma unroll
        for (int q2 = 0; q2 < 4; ++q2) {
          wh[q2] = *(const bf16x8*)(tb + q2 * 512);
          wl[q2] = *(const bf16x8*)(tb + 4096 + q2 * 512);
        }
        f32x4 aH = {0.f,0.f,0.f,0.f}, aL = {0.f,0.f,0.f,0.f};
        #pragma unroll
        for (int kc = 0; kc < 8; ++kc) {
          const int cur = kc & 3;
          aH = mfma16(ah[kc], wh[cur], aH);
          aL = mfma16(ah[kc], wl[cur], aL);
          if (kc + 4 < 8) {
            wh[cur] = *(const bf16x8*)(tb + (kc + 4) * 512);
            wl[cur] = *(const bf16x8*)(tb + 4096 + (kc + 4) * 512);
          }
        }
        f32x4 acc = aH + aL;
        float s0 = acc[0] + __shfl_xor(acc[0], 16, 64);
        float s1 = acc[1] + __shfl_xor(acc[1], 16, 64);
        float s2 = acc[2] + __shfl_xor(acc[2], 16, 64);
        float s3 = acc[3] + __shfl_xor(acc[3], 16, 64);
        if (l < 16) {
          const int g = nt * 16 + l;
          gsh[0][g] = s0; gsh[1][g] = s1; gsh[2][g] = s2; gsh[3][g] = s3;
        }
      }
    }
    __syncthreads();
  }
}

// ---------------- mainK6: fallback (round-6-proven, no xw table) ----------------
__global__ __launch_bounds__(512)
__attribute__((amdgpu_waves_per_eu(2, 2)))
void mainK6(const void* targets, const void* h0, const void* c0, const void* vt,
            float* ws, void* outp) {
  __shared__ __align__(16) unsigned short hS[16][264];
  __shared__ __align__(16) unsigned short xA[16][136];
  __shared__ float cT[8][256];
  __shared__ float gsh[8][1024];
  __shared__ float bias_s[1024];
  __shared__ float b2s[8][64];
  __shared__ float outs[8][64];
  __shared__ float vt_s[64];
  __shared__ int   selidx[8];
  __shared__ int   selb[8][64];

  const int b16 = ((const int*)ws)[0];
  const int t = threadIdx.x;
  const int bbase = blockIdx.x * 8;
  const unsigned short* wb = (const unsigned short*)(ws + O_WB);

  for (int k = t; k < 1024; k += 512) bias_s[k] = ws[O_BIAS + k];
  if (t < 64) vt_s[t] = ldv(vt, b16, t);
  if (t < 512) selb[t >> 6][t & 63] = 0;
  if (t < 8) selidx[t] = -1;
  {
    unsigned short* z1 = &hS[0][0];
    unsigned short* z2 = &xA[0][0];
    for (int k = t; k < 16 * 264; k += 512) z1[k] = 0;
    for (int k = t; k < 16 * 136; k += 512) z2[k] = 0;
  }
  __syncthreads();
  for (int k = t; k < 2048; k += 512) {
    int p = k >> 8, j = k & 255;
    float h = ldv(h0, b16, (long long)(bbase + p) * 256 + j);
    float c = ldv(c0, b16, (long long)(bbase + p) * 256 + j);
    unsigned short hi = f2b(h);
    hS[p][j]     = hi;
    hS[p + 8][j] = f2b(h - b2f((unsigned int)hi));
    cT[p][j]     = c;
  }
  __syncthreads();

  const int l  = t & 63, Wv = t >> 6;
  const int lr = l & 15;

  #pragma unroll 1
  for (int step = 0; step < 50; ++step) {
    {
      bf16x8 ah[8], ax[4];
      #pragma unroll
      for (int kc = 0; kc < 8; ++kc)
        ah[kc] = *(const bf16x8*)&hS[lr][kc * 32 + (l >> 4) * 8];
      #pragma unroll
      for (int kc = 0; kc < 4; ++kc)
        ax[kc] = *(const bf16x8*)&xA[lr][kc * 32 + (l >> 4) * 8];
      #pragma unroll 1
      for (int ti = 0; ti < 8; ++ti) {
        const int nt = Wv * 8 + ti;
        const unsigned short* tb = wb + (long long)nt * WB_TILE + l * 8;
        bf16x8 wH[12], wL[12];
        #pragma unroll
        for (int kc = 0; kc < 8; ++kc) {
          wH[kc] = *(const bf16x8*)(tb + kc * 512);
          wL[kc] = *(const bf16x8*)(tb + 4096 + kc * 512);
        }
        #pragma unroll
        for (int kc = 0; kc < 4; ++kc) {
          wH[8 + kc] = *(const bf16x8*)(tb + 8192 + kc * 512);
          wL[8 + kc] = *(const bf16x8*)(tb + 10240 + kc * 512);
        }
        f32x4 aH = {0.f,0.f,0.f,0.f}, aL = {0.f,0.f,0.f,0.f};
        #pragma unroll
        for (int kc = 0; kc < 8; ++kc) {
          aH = mfma16(ah[kc], wH[kc], aH);
          aL = mfma16(ah[kc], wL[kc], aL);
        }
        #pragma unroll
        for (int kc = 0; kc < 4; ++kc) {
          aH = mfma16(ax[kc], wH[8 + kc], aH);
          aL = mfma16(ax[kc], wL[8 + kc], aL);
        }
        f32x4 acc = aH + aL;
        float s0 = acc[0] + __shfl_xor(acc[0], 32, 64);
        float s1 = acc[1] + __shfl_xor(acc[1], 32, 64);
        float s2 = acc[2] + __shfl_xor(acc[2], 32, 64);
        float s3 = acc[3] + __shfl_xor(acc[3], 32, 64);
        if (l < 32) {
          const int g = nt * 16 + (l & 15), pb = (l >> 4) * 4;
          gsh[pb + 0][g] = s0; gsh[pb + 1][g] = s1;
          gsh[pb + 2][g] = s2; gsh[pb + 3][g] = s3;
        }
      }
    }
    __syncthreads();

    for (int k = t; k < 2048; k += 512) {
      int j = k & 255, p = k >> 8;
      float gi = sigm (gsh[p][j]       + bias_s[j]);
      float gf = sigm (gsh[p][256 + j] + bias_s[256 + j]);
      float gg = tanhx(gsh[p][512 + j] + bias_s[512 + j]);
      float go = sigm (gsh[p][768 + j] + bias_s[768 + j]);
      float c = gf * cT[p][j] + gi * gg;
      cT[p][j] = c;
      float h = go * tanhx(c);
      unsigned short hi = f2b(h);
      hS[p][j]     = hi;
      hS[p + 8][j] = f2b(h - b2f((unsigned int)hi));
    }
    __syncthreads();

    if (Wv < 4) {
      bf16x8 bh[8];
      #pragma unroll
      for (int kc = 0; kc < 8; ++kc)
        bh[kc] = *(const bf16x8*)&hS[lr][kc * 32 + (l >> 4) * 8];
      const unsigned short* tb = wb + WB_W2 + Wv * 8192 + l * 8;
      f32x4 aH = {0.f,0.f,0.f,0.f}, aL = {0.f,0.f,0.f,0.f};
      #pragma unroll
      for (int kc = 0; kc < 8; ++kc) {
        aH = mfma16(bh[kc], *(const bf16x8*)(tb + kc * 512), aH);
        aL = mfma16(bh[kc], *(const bf16x8*)(tb + 4096 + kc * 512), aL);
      }
      f32x4 acc = aH + aL;
      float s0 = acc[0] + __shfl_xor(acc[0], 32, 64);
      float s1 = acc[1] + __shfl_xor(acc[1], 32, 64);
      float s2 = acc[2] + __shfl_xor(acc[2], 32, 64);
      float s3 = acc[3] + __shfl_xor(acc[3], 32, 64);
      if (l < 32) {
        const int g = Wv * 16 + (l & 15), pb = (l >> 4) * 4;
        b2s[pb + 0][g] = s0; b2s[pb + 1][g] = s1;
        b2s[pb + 2][g] = s2; b2s[pb + 3][g] = s3;
      }
    }
    __syncthreads();

    if (t < 400) {
      int p = t / 50, j = t - p * 50;
      const float* bl = ws + O_BLEND1 + (((bbase + p) * 50 + j) * 64);
      float acc = 0.f;
      #pragma unroll
      for (int v4 = 0; v4 < 16; ++v4) {
        float4 bv = *(const float4*)(bl + v4 * 4);
        int w0 = v4 * 4;
        acc += vt_s[w0 + 0] * tanhx(bv.x + b2s[p][w0 + 0]);
        acc += vt_s[w0 + 1] * tanhx(bv.y + b2s[p][w0 + 1]);
        acc += vt_s[w0 + 2] * tanhx(bv.z + b2s[p][w0 + 2]);
        acc += vt_s[w0 + 3] * tanhx(bv.w + b2s[p][w0 + 3]);
      }
      outs[p][j] = selb[p][j] ? NEG_INF_V : acc;
    }
    __syncthreads();

    {
      int p = Wv, lane = l;
      float v = (lane < 50) ? outs[p][lane] : -3.4e38f;
      int idx = lane;
      #pragma unroll
      for (int msk = 1; msk < 64; msk <<= 1) {
        float ov = __shfl_xor(v, msk, 64);
        int   oi = __shfl_xor(idx, msk, 64);
        if (ov > v || (ov == v && oi < idx)) { v = ov; idx = oi; }
      }
      float e = (lane < 50) ? __expf(outs[p][lane] - v) : 0.f;
      float ssum = e;
      #pragma unroll
      for (int msk = 1; msk < 64; msk <<= 1) ssum += __shfl_xor(ssum, msk, 64);
      if (lane < 50) {
        float prob = fmaxf(e / ssum, 1e-9f);
        int o = (bbase + p) * 2500 + step * 50 + lane;
        if (b16) ((unsigned short*)outp)[o] = f2b(prob);
        else     ((float*)outp)[o] = prob;
      }
      if (lane == 0) selidx[p] = idx;
      if (lane == idx) selb[p][idx] = 1;
    }
    __syncthreads();

    for (int k = t; k < 1024; k += 512) {
      int p = k >> 7, i = k & 127;
      float xf = ldv(targets, b16,
                     ((long long)(bbase + p) * 50 + selidx[p]) * 128 + i);
      unsigned short hi = f2b(xf);
      xA[p][i]     = hi;
      xA[p + 8][i] = f2b(xf - b2f((unsigned int)hi));
    }
    __syncthreads();
  }
}

extern "C" void kernel_launch(void* const* d_in, const int* in_sizes, int n_in,
                              void* d_out, int out_size, void* d_ws, size_t ws_size,
                              hipStream_t stream) {
  (void)in_sizes; (void)n_in; (void)out_size;
  const void* targets = d_in[0];
  const void* h0      = d_in[1];
  const void* c0      = d_in[2];
  const void* W_enc   = d_in[3];
  const void* b_enc   = d_in[4];
  const void* W_ih    = d_in[5];
  const void* W_hh    = d_in[6];
  const void* b_ih    = d_in[7];
  const void* b_hh    = d_in[8];
  const void* W1      = d_in[9];
  const void* W2      = d_in[10];
  const void* vt      = d_in[11];
  float* ws = (float*)d_ws;

  int use_xw = (ws_size >= ((size_t)O_XW + (size_t)XW_FLOATS) * 4) ? 1 : 0;

  prepAll<<<1056, 256, 0, stream>>>(b_enc, b_ih, b_hh, W1, W_ih, W_hh, W2,
                                    W_enc, ws);
  blendk<<<1024, 256, 0, stream>>>(targets, ws);
  if (use_xw) {
    xwK<<<256, 512, 0, stream>>>(targets, ws);
    mainX<<<256, 1024, 0, stream>>>(targets, h0, c0, vt, ws, d_out);
  } else {
    mainK6<<<128, 512, 0, stream>>>(targets, h0, c0, vt, ws, d_out);
  }
}